// Round 10
// baseline (371.521 us; speedup 1.0000x reference)
//
#include <hip/hip_runtime.h>

#define BATCH 8
#define DIMC 128
#define NTOT 32768
#define HEADS 4
#define DHEAD 32
#define SCALE_Q 0.17677669529663687f
#define GRIDX 64
#define TILES 8   // GRIDX * TILES * 64 == NTOT

typedef _Float16 half8  __attribute__((ext_vector_type(8)));
typedef _Float16 half4v __attribute__((ext_vector_type(4)));
typedef float    f32x4  __attribute__((ext_vector_type(4)));

// workspace byte offsets (all 16B aligned)
#define WS_WQKV 0        // _Float16[384*128]   = 98304 B
#define WS_S    98304    // float[8*4*32*32]    = 131072 B
#define WS_Z    229376   // float[8*4*32]       = 4096 B
#define WS_ST   233472   // float[16]           (64 B)
#define WS_NEED 233536

// d_out row layout (each row 131072 B): LOWER half = Ê[b][d][0..32767] f16 (K1 writes,
// K3 reads); UPPER half = y f16 stash (K3 writes, K4 reads row-locally then overwrites).

// ---------------- K0: convert Wqkv to f16, zero accumulators ----------------
__global__ void k0_prep(const float* __restrict__ wqkv, char* __restrict__ ws) {
    int i = blockIdx.x * 256 + threadIdx.x;
    _Float16* Wb = (_Float16*)(ws + WS_WQKV);
    float* S  = (float*)(ws + WS_S);
    float* Z  = (float*)(ws + WS_Z);
    float* St = (float*)(ws + WS_ST);
    if (i < 49152) Wb[i] = (_Float16)wqkv[i];
    int j = i - 49152;
    if (j >= 0 && j < 32768) S[j] = 0.f;
    int k = j - 32768;
    if (k >= 0 && k < 1024) Z[k] = 0.f;
    int m = k - 1024;
    if (m >= 0 && m < 16) St[m] = 0.f;
}

// ---------------- K1: full qkv projection. k,v -> S,Z atomics; q -> Ê f16 (d_out lower halves) ----------------
__global__ __launch_bounds__(256, 2) void k1_kv(const float* __restrict__ x,
                                                const _Float16* __restrict__ Wb,
                                                float* __restrict__ S,
                                                float* __restrict__ Z,
                                                char* __restrict__ ybase) {
    __shared__ _Float16 Xb[64][136];   // x^T tile: [j][c swizzled]
    __shared__ _Float16 KB[128][64];   // exp(k): [h*32+d][j swizzled]
    __shared__ _Float16 VB[128][64];   // v:      [h*32+e][j swizzled]
    const int t = threadIdx.x;
    const int lane = t & 63, w = t >> 6, g = lane >> 4, l15 = lane & 15;
    const int b = blockIdx.y;

    half8 af[4][4];  // k,v weight frags (rows 128..383)
    half8 wa[2][4];  // q weight frags (rows 0..127, head w)
#pragma unroll
    for (int mt = 0; mt < 4; ++mt)
#pragma unroll
        for (int kc = 0; kc < 4; ++kc)
            af[mt][kc] = *(const half8*)(Wb + (size_t)(128 + (w * 4 + mt) * 16 + l15) * 128 + kc * 32 + 8 * g);
#pragma unroll
    for (int mi = 0; mi < 2; ++mi)
#pragma unroll
        for (int kc = 0; kc < 4; ++kc)
            wa[mi][kc] = *(const half8*)(Wb + (size_t)((w * 2 + mi) * 16 + l15) * 128 + kc * 32 + 8 * g);

    f32x4 sacc[2][2];
#pragma unroll
    for (int dm = 0; dm < 2; ++dm)
#pragma unroll
        for (int en = 0; en < 2; ++en) sacc[dm][en] = (f32x4){0.f, 0.f, 0.f, 0.f};
    float zpart = 0.f;

    const int j4 = t & 15, c0 = t >> 4;
    const int sxw = (j4 & 7) << 3;

    // prologue: load + stage tile 0
    float4 xr[8];
#pragma unroll
    for (int cc = 0; cc < 8; ++cc)
        xr[cc] = *(const float4*)(x + ((size_t)b * DIMC + c0 + 16 * cc) * NTOT + blockIdx.x * 64 + 4 * j4);
#pragma unroll
    for (int cc = 0; cc < 8; ++cc) {
        const int c = c0 + 16 * cc;
        Xb[4 * j4 + 0][c ^ sxw] = (_Float16)xr[cc].x;
        Xb[4 * j4 + 1][c ^ sxw] = (_Float16)xr[cc].y;
        Xb[4 * j4 + 2][c ^ sxw] = (_Float16)xr[cc].z;
        Xb[4 * j4 + 3][c ^ sxw] = (_Float16)xr[cc].w;
    }

    for (int it = 0; it < TILES; ++it) {
        const int j0 = (blockIdx.x + GRIDX * it) * 64;
        if (it < TILES - 1) {
            const int j0n = (blockIdx.x + GRIDX * (it + 1)) * 64;
#pragma unroll
            for (int cc = 0; cc < 8; ++cc)
                xr[cc] = *(const float4*)(x + ((size_t)b * DIMC + c0 + 16 * cc) * NTOT + j0n + 4 * j4);
        }
        __syncthreads();   // Xb(tile it) visible; prev-iter KB/VB reads done
        half8 bf[4][4];
#pragma unroll
        for (int nt = 0; nt < 4; ++nt) {
            const int sb = ((4 * nt + (l15 >> 2)) & 7) << 3;
#pragma unroll
            for (int kc = 0; kc < 4; ++kc)
                bf[nt][kc] = *(const half8*)(&Xb[nt * 16 + l15][(kc * 32 + 8 * g) ^ sb]);
        }
        // q part: E=exp(q), per-column colsum, write Ê f16 to d_out lower halves
        {
            f32x4 eacc[2][4];
#pragma unroll
            for (int mi = 0; mi < 2; ++mi)
#pragma unroll
                for (int nt = 0; nt < 4; ++nt) eacc[mi][nt] = (f32x4){0.f, 0.f, 0.f, 0.f};
#pragma unroll
            for (int mi = 0; mi < 2; ++mi)
#pragma unroll
                for (int kc = 0; kc < 4; ++kc)
#pragma unroll
                    for (int nt = 0; nt < 4; ++nt)
                        eacc[mi][nt] = __builtin_amdgcn_mfma_f32_16x16x32_f16(wa[mi][kc], bf[nt][kc], eacc[mi][nt], 0, 0, 0);
            float ps[4] = {0.f, 0.f, 0.f, 0.f};
#pragma unroll
            for (int mi = 0; mi < 2; ++mi)
#pragma unroll
                for (int nt = 0; nt < 4; ++nt)
#pragma unroll
                    for (int r = 0; r < 4; ++r) {
                        const float e = __expf(eacc[mi][nt][r]);
                        ps[nt] += e;
                        eacc[mi][nt][r] = e;
                    }
            float scn[4];
#pragma unroll
            for (int nt = 0; nt < 4; ++nt) {
                ps[nt] += __shfl_xor(ps[nt], 16);
                ps[nt] += __shfl_xor(ps[nt], 32);
                scn[nt] = SCALE_Q / ps[nt];
            }
#pragma unroll
            for (int mi = 0; mi < 2; ++mi)
#pragma unroll
                for (int r = 0; r < 4; ++r) {
                    const int d = (w * 2 + mi) * 16 + g * 4 + r;
                    _Float16* erow = (_Float16*)(ybase + (size_t)(b * DIMC + d) * 131072);
#pragma unroll
                    for (int nt = 0; nt < 4; ++nt)
                        erow[j0 + nt * 16 + l15] = (_Float16)(eacc[mi][nt][r] * scn[nt]);
                }
        }
        // k,v part
#pragma unroll
        for (int mt = 0; mt < 4; ++mt) {
            f32x4 a0 = (f32x4){0.f,0.f,0.f,0.f}, a1 = a0, a2 = a0, a3 = a0;
#pragma unroll
            for (int kc = 0; kc < 4; ++kc) {
                a0 = __builtin_amdgcn_mfma_f32_16x16x32_f16(af[mt][kc], bf[0][kc], a0, 0, 0, 0);
                a1 = __builtin_amdgcn_mfma_f32_16x16x32_f16(af[mt][kc], bf[1][kc], a1, 0, 0, 0);
                a2 = __builtin_amdgcn_mfma_f32_16x16x32_f16(af[mt][kc], bf[2][kc], a2, 0, 0, 0);
                a3 = __builtin_amdgcn_mfma_f32_16x16x32_f16(af[mt][kc], bf[3][kc], a3, 0, 0, 0);
            }
            const int lr0 = (w * 4 + mt) * 16 + g * 4;
            const int skv = (((w * 4 + mt) * 4 + g) & 7) << 3;
#pragma unroll
            for (int nt = 0; nt < 4; ++nt) {
                const f32x4 a = (nt == 0) ? a0 : (nt == 1) ? a1 : (nt == 2) ? a2 : a3;
                const int jn = (nt * 16 + l15) ^ skv;
                if (lr0 < 128) {
#pragma unroll
                    for (int r = 0; r < 4; ++r) KB[lr0 + r][jn] = (_Float16)__expf(a[r]);
                } else {
#pragma unroll
                    for (int r = 0; r < 4; ++r) VB[lr0 - 128 + r][jn] = (_Float16)a[r];
                }
            }
        }
        __syncthreads();   // KB/VB ready; Xb reads done
        // stage tile it+1 into Xb, overlapping the S/Z phase
        if (it < TILES - 1) {
#pragma unroll
            for (int cc = 0; cc < 8; ++cc) {
                const int c = c0 + 16 * cc;
                Xb[4 * j4 + 0][c ^ sxw] = (_Float16)xr[cc].x;
                Xb[4 * j4 + 1][c ^ sxw] = (_Float16)xr[cc].y;
                Xb[4 * j4 + 2][c ^ sxw] = (_Float16)xr[cc].z;
                Xb[4 * j4 + 3][c ^ sxw] = (_Float16)xr[cc].w;
            }
        }
#pragma unroll
        for (int dm = 0; dm < 2; ++dm) {
            const int sr = ((4 * dm + (l15 >> 2)) & 7) << 3;
#pragma unroll
            for (int en = 0; en < 2; ++en)
#pragma unroll
                for (int kc = 0; kc < 2; ++kc) {
                    half8 ka = *(const half8*)(&KB[w * 32 + dm * 16 + l15][(kc * 32 + 8 * g) ^ sr]);
                    half8 vb = *(const half8*)(&VB[w * 32 + en * 16 + l15][(kc * 32 + 8 * g) ^ sr]);
                    sacc[dm][en] = __builtin_amdgcn_mfma_f32_16x16x32_f16(ka, vb, sacc[dm][en], 0, 0, 0);
                }
        }
        {
            const int zr = lane >> 1;
            const int sz = ((zr >> 2) & 7) << 3;
#pragma unroll
            for (int s8 = 0; s8 < 4; ++s8) {
                half8 hv = *(const half8*)(&KB[w * 32 + zr][((lane & 1) * 32 + 8 * s8) ^ sz]);
#pragma unroll
                for (int e = 0; e < 8; ++e) zpart += (float)hv[e];
            }
        }
    }
    {
        float zt = zpart + __shfl_xor(zpart, 1);
        if ((lane & 1) == 0) atomicAdd(&Z[(b * HEADS + w) * DHEAD + (lane >> 1)], zt);
    }
#pragma unroll
    for (int dm = 0; dm < 2; ++dm)
#pragma unroll
        for (int en = 0; en < 2; ++en)
#pragma unroll
            for (int r = 0; r < 4; ++r)
                atomicAdd(&S[((size_t)(b * HEADS + w) * DHEAD + dm * 16 + g * 4 + r) * DHEAD + en * 16 + l15],
                          sacc[dm][en][r]);
}

// ---------------- K3: streaming y = G @ Ê + b (G frags computed in prologue from S,Z,wout) ----------------
__global__ __launch_bounds__(256, 2) void k3_main(const float* __restrict__ S,
                                                  const float* __restrict__ Z,
                                                  const float* __restrict__ wout,
                                                  const float* __restrict__ b_out,
                                                  char* __restrict__ ybase,
                                                  float* __restrict__ St) {
    __shared__ _Float16 EB[64][136];  // Ê tile transposed: [j][d swizzled]
    __shared__ float red[8];
    const int t = threadIdx.x;
    const int lane = t & 63, w = t >> 6, g = lane >> 4, l15 = lane & 15;
    const int b = blockIdx.y;

    // prologue: ga[mi][kc] = G rows (w*2+mi)*16+l15, cols kc*32+8g..+7
    // G[o][h*32+dd] = sum_e wout[o][h*32+e] * S[b][h][dd][e] / Z[b][h][dd], h=kc
    half8 ga[2][4];
    float bo[2][4];
#pragma unroll
    for (int mi = 0; mi < 2; ++mi) {
        const int o = (w * 2 + mi) * 16 + l15;
#pragma unroll
        for (int r = 0; r < 4; ++r) bo[mi][r] = b_out[(w * 2 + mi) * 16 + g * 4 + r];
#pragma unroll
        for (int kc = 0; kc < 4; ++kc) {
            float wrow[32];
#pragma unroll
            for (int e = 0; e < 32; ++e) wrow[e] = wout[o * 128 + kc * 32 + e];
            half8 gv;
#pragma unroll
            for (int q = 0; q < 8; ++q) {
                const int dd = 8 * g + q;
                const float* srow = S + ((size_t)((b * HEADS + kc) * DHEAD + dd)) * DHEAD;
                const float rz = 1.0f / Z[(b * HEADS + kc) * DHEAD + dd];
                float acc = 0.f;
#pragma unroll
                for (int e = 0; e < 32; ++e) acc = fmaf(wrow[e], srow[e], acc);
                gv[q] = (_Float16)(acc * rz);
            }
            ga[mi][kc] = gv;
        }
    }

    float ssum = 0.f, ssq = 0.f;
    half8 er[4];

    // stage tile 0
#pragma unroll
    for (int p = 0; p < 4; ++p) {
        const int idx = p * 256 + t, d = idx >> 3, jj = (idx & 7) * 8;
        er[p] = *(const half8*)((const _Float16*)(ybase + (size_t)(b * DIMC + d) * 131072) + blockIdx.x * 64 + jj);
    }
#pragma unroll
    for (int p = 0; p < 4; ++p) {
        const int idx = p * 256 + t, d = idx >> 3, jj = (idx & 7) * 8;
#pragma unroll
        for (int e = 0; e < 8; ++e) EB[jj + e][d ^ ((((jj + e) >> 2) & 7) << 3)] = er[p][e];
    }
    __syncthreads();

    for (int it = 0; it < TILES; ++it) {
        const int j0 = (blockIdx.x + GRIDX * it) * 64;
        if (it < TILES - 1) {
            const int j0n = (blockIdx.x + GRIDX * (it + 1)) * 64;
#pragma unroll
            for (int p = 0; p < 4; ++p) {
                const int idx = p * 256 + t, d = idx >> 3, jj = (idx & 7) * 8;
                er[p] = *(const half8*)((const _Float16*)(ybase + (size_t)(b * DIMC + d) * 131072) + j0n + jj);
            }
        }
        // y-GEMM from EB
        {
            half8 bf[4][4];
#pragma unroll
            for (int nt = 0; nt < 4; ++nt) {
                const int sb = ((4 * nt + (l15 >> 2)) & 7) << 3;
#pragma unroll
                for (int kc = 0; kc < 4; ++kc)
                    bf[nt][kc] = *(const half8*)(&EB[nt * 16 + l15][(kc * 32 + 8 * g) ^ sb]);
            }
#pragma unroll
            for (int mi = 0; mi < 2; ++mi) {
                const int o0 = (w * 2 + mi) * 16 + g * 4;
                f32x4 acc[4];
#pragma unroll
                for (int nt = 0; nt < 4; ++nt) acc[nt] = (f32x4){0.f, 0.f, 0.f, 0.f};
#pragma unroll
                for (int kc = 0; kc < 4; ++kc)
#pragma unroll
                    for (int nt = 0; nt < 4; ++nt)
                        acc[nt] = __builtin_amdgcn_mfma_f32_16x16x32_f16(ga[mi][kc], bf[nt][kc], acc[nt], 0, 0, 0);
#pragma unroll
                for (int r = 0; r < 4; ++r) {
                    _Float16* yrow = (_Float16*)(ybase + (size_t)(b * DIMC + o0 + r) * 131072 + 65536);
#pragma unroll
                    for (int nt = 0; nt < 4; ++nt) {
                        const float yv = acc[nt][r] + bo[mi][r];
                        ssum += yv;
                        ssq += yv * yv;
                        yrow[j0 + nt * 16 + l15] = (_Float16)yv;
                    }
                }
            }
        }
        __syncthreads();   // EB reads done
        if (it < TILES - 1) {
#pragma unroll
            for (int p = 0; p < 4; ++p) {
                const int idx = p * 256 + t, d = idx >> 3, jj = (idx & 7) * 8;
#pragma unroll
                for (int e = 0; e < 8; ++e) EB[jj + e][d ^ ((((jj + e) >> 2) & 7) << 3)] = er[p][e];
            }
        }
        __syncthreads();   // EB(next) ready
    }
#pragma unroll
    for (int m = 32; m; m >>= 1) { ssum += __shfl_xor(ssum, m); ssq += __shfl_xor(ssq, m); }
    if (lane == 0) { red[w] = ssum; red[4 + w] = ssq; }
    __syncthreads();
    if (t == 0) {
        atomicAdd(&St[b * 2 + 0], red[0] + red[1] + red[2] + red[3]);
        atomicAdd(&St[b * 2 + 1], red[4] + red[5] + red[6] + red[7]);
    }
}

// ---------------- K4: layernorm; read f16 stash (2nd half of own row), write f32 ----------------
__global__ __launch_bounds__(256) void k4_norm(float* __restrict__ out, const float* __restrict__ St,
                                               const float* __restrict__ gamma,
                                               const float* __restrict__ beta) {
    const int o = blockIdx.x;
    const int b = blockIdx.y;
    const int t = threadIdx.x;
    const size_t row = (size_t)b * DIMC + o;
    const float n = (float)DIMC * (float)NTOT;
    const float mean = St[b * 2] / n;
    const float var = St[b * 2 + 1] / n - mean * mean;
    const float rs = rsqrtf(var + 1e-5f);
    const float ga = gamma[o] * rs;
    const float be = beta[o];
    const half8* yh = (const half8*)((const char*)out + row * 131072 + 65536);
    half8 hbuf[16];
#pragma unroll
    for (int i = 0; i < 16; ++i) hbuf[i] = yh[i * 256 + t];
    __syncthreads();  // all reads before any f32 overwrite (stash lives in this row)
    float4* orow = (float4*)(out + row * NTOT);
#pragma unroll
    for (int i = 0; i < 16; ++i) {
        const int e4 = (i * 256 + t) * 2;
        float4 v0, v1;
        v0.x = ((float)hbuf[i][0] - mean) * ga + be;
        v0.y = ((float)hbuf[i][1] - mean) * ga + be;
        v0.z = ((float)hbuf[i][2] - mean) * ga + be;
        v0.w = ((float)hbuf[i][3] - mean) * ga + be;
        v1.x = ((float)hbuf[i][4] - mean) * ga + be;
        v1.y = ((float)hbuf[i][5] - mean) * ga + be;
        v1.z = ((float)hbuf[i][6] - mean) * ga + be;
        v1.w = ((float)hbuf[i][7] - mean) * ga + be;
        orow[e4] = v0;
        orow[e4 + 1] = v1;
    }
}

extern "C" void kernel_launch(void* const* d_in, const int* in_sizes, int n_in,
                              void* d_out, int out_size, void* d_ws, size_t ws_size,
                              hipStream_t stream) {
    const float* x     = (const float*)d_in[0];
    const float* wqkv  = (const float*)d_in[1];
    const float* wout  = (const float*)d_in[2];
    const float* b_out = (const float*)d_in[3];
    const float* gamma = (const float*)d_in[4];
    const float* beta  = (const float*)d_in[5];
    if (ws_size < WS_NEED) return;
    char* ws = (char*)d_ws;
    _Float16* Wb = (_Float16*)(ws + WS_WQKV);
    float* S  = (float*)(ws + WS_S);
    float* Z  = (float*)(ws + WS_Z);
    float* St = (float*)(ws + WS_ST);

    k0_prep<<<325, 256, 0, stream>>>(wqkv, ws);
    k1_kv<<<dim3(GRIDX, 8), 256, 0, stream>>>(x, Wb, S, Z, (char*)d_out);
    k3_main<<<dim3(GRIDX, 8), 256, 0, stream>>>(S, Z, wout, b_out, (char*)d_out, St);
    k4_norm<<<dim3(128, 8), 256, 0, stream>>>((float*)d_out, St, gamma, beta);
}

// Round 11
// 251.873 us; speedup vs baseline: 1.4750x; 1.4750x over previous
//
#include <hip/hip_runtime.h>

#define BATCH 8
#define DIMC 128
#define NTOT 32768
#define HEADS 4
#define DHEAD 32
#define SCALE_Q 0.17677669529663687f
#define GRIDX 64
#define TILES 8   // GRIDX * TILES * 64 == NTOT

typedef _Float16 half8  __attribute__((ext_vector_type(8)));
typedef _Float16 half4v __attribute__((ext_vector_type(4)));
typedef float    f32x4  __attribute__((ext_vector_type(4)));

// workspace byte offsets (all 16B aligned); ws_size >= 331840 proven in rounds 4-5
#define WS_WQKV 0        // _Float16[384*128]   = 98304 B
#define WS_S    98304    // float[8*4*32*32]    = 131072 B
#define WS_Z    229376   // float[8*4*32]       = 4096 B
#define WS_ST   233472   // float[16]           (64 B)
#define WS_G    233536   // _Float16[8*128*128] = 65536 B... (8 * 32768 B = 262144? no: 8*16384*2 = 262144)
// NOTE: G is 128x128 f16 per batch = 32768 B; 8 batches = 262144 B -> too big after ST.
// Instead store G per-batch f16 at WS_G with stride 32768 B: need 262144 -> WS_NEED 495680 > proven.
// FIX: store G as f16 but only 8*32768 = 262144 exceeds proven ws. Use d_out scratch instead:
// G[b] lives in the UPPER half of d_out row (b*16+8)..? No: stash conflicts.
// Resolution: G[b] f16 (32 KB) -> ws is fine if we drop Wb... Wb needed. Use lower halves of
// d_out rows 896..903 (b=7 region)? Ê occupies ALL lower halves. Use ws: drop WS_WQKV after K1?
// k2_g runs after K1; K3 reads Wb? No - K3' no longer reads Wb. So G can OVERWRITE WS_WQKV.
#define WS_GOFF 0        // G[b] at ws + b*32768 (overwrites Wb region 0..262144; Wb dead after K1)
#define WS_NEED 299072

// d_out row layout (each row 131072 B): LOWER half = Ê[b][d][j] f16 (K1 writes, K3 reads);
// UPPER half = y f16 stash (K3 writes, K4 reads row-locally then overwrites with f32).

// ---------------- K0: convert Wqkv to f16, zero accumulators ----------------
__global__ void k0_prep(const float* __restrict__ wqkv, char* __restrict__ ws) {
    int i = blockIdx.x * 256 + threadIdx.x;
    _Float16* Wb = (_Float16*)(ws + WS_WQKV);
    float* S  = (float*)(ws + WS_S);
    float* Z  = (float*)(ws + WS_Z);
    float* St = (float*)(ws + WS_ST);
    if (i < 49152) Wb[i] = (_Float16)wqkv[i];
    int j = i - 49152;
    if (j >= 0 && j < 32768) S[j] = 0.f;
    int k = j - 32768;
    if (k >= 0 && k < 1024) Z[k] = 0.f;
    int m = k - 1024;
    if (m >= 0 && m < 16) St[m] = 0.f;
}

// ---------------- K1: qkv projection; k,v -> S,Z; q -> Ê (softmax'd, f16, d_out lower halves) ----------------
__global__ __launch_bounds__(256, 2) void k1_kv(const float* __restrict__ x,
                                                const _Float16* __restrict__ Wb,
                                                float* __restrict__ S,
                                                float* __restrict__ Z,
                                                char* __restrict__ ybase) {
    __shared__ _Float16 Xb[64][136];   // x^T tile: [j][c swizzled]
    __shared__ _Float16 KB[128][64];   // exp(k): [h*32+d][j swizzled]
    __shared__ _Float16 VB[128][64];   // v:      [h*32+e][j swizzled]
    __shared__ _Float16 EQ[128][64];   // Ê:      [d][j swizzled]
    const int t = threadIdx.x;
    const int lane = t & 63, w = t >> 6, g = lane >> 4, l15 = lane & 15;
    const int b = blockIdx.y;

    // hoist only wa (32 VGPR); af loaded per-mt in-loop (register budget — R10 spilled with both)
    half8 wa[2][4];
#pragma unroll
    for (int mi = 0; mi < 2; ++mi)
#pragma unroll
        for (int kc = 0; kc < 4; ++kc)
            wa[mi][kc] = *(const half8*)(Wb + (size_t)((w * 2 + mi) * 16 + l15) * 128 + kc * 32 + 8 * g);

    f32x4 sacc[2][2];
#pragma unroll
    for (int dm = 0; dm < 2; ++dm)
#pragma unroll
        for (int en = 0; en < 2; ++en) sacc[dm][en] = (f32x4){0.f, 0.f, 0.f, 0.f};
    float zpart = 0.f;

    const int j4 = t & 15, c0 = t >> 4;
    const int sxw = (j4 & 7) << 3;

    // prologue: load + stage tile 0
    float4 xr[8];
#pragma unroll
    for (int cc = 0; cc < 8; ++cc)
        xr[cc] = *(const float4*)(x + ((size_t)b * DIMC + c0 + 16 * cc) * NTOT + blockIdx.x * 64 + 4 * j4);
#pragma unroll
    for (int cc = 0; cc < 8; ++cc) {
        const int c = c0 + 16 * cc;
        Xb[4 * j4 + 0][c ^ sxw] = (_Float16)xr[cc].x;
        Xb[4 * j4 + 1][c ^ sxw] = (_Float16)xr[cc].y;
        Xb[4 * j4 + 2][c ^ sxw] = (_Float16)xr[cc].z;
        Xb[4 * j4 + 3][c ^ sxw] = (_Float16)xr[cc].w;
    }

    for (int it = 0; it < TILES; ++it) {
        const int j0 = (blockIdx.x + GRIDX * it) * 64;
        if (it < TILES - 1) {
            const int j0n = (blockIdx.x + GRIDX * (it + 1)) * 64;
#pragma unroll
            for (int cc = 0; cc < 8; ++cc)
                xr[cc] = *(const float4*)(x + ((size_t)b * DIMC + c0 + 16 * cc) * NTOT + j0n + 4 * j4);
        }
        __syncthreads();   // (A) Xb ready; prev KB/VB/EQ reads done
        half8 bf[4][4];
#pragma unroll
        for (int nt = 0; nt < 4; ++nt) {
            const int sb = ((4 * nt + (l15 >> 2)) & 7) << 3;
#pragma unroll
            for (int kc = 0; kc < 4; ++kc)
                bf[nt][kc] = *(const half8*)(&Xb[nt * 16 + l15][(kc * 32 + 8 * g) ^ sb]);
        }
        // q part: E=exp(q), per-column colsum over head w, Ê = E*SCALE/colsum -> EQ LDS
        {
            f32x4 eacc[2][4];
#pragma unroll
            for (int mi = 0; mi < 2; ++mi)
#pragma unroll
                for (int nt = 0; nt < 4; ++nt) eacc[mi][nt] = (f32x4){0.f, 0.f, 0.f, 0.f};
#pragma unroll
            for (int mi = 0; mi < 2; ++mi)
#pragma unroll
                for (int kc = 0; kc < 4; ++kc)
#pragma unroll
                    for (int nt = 0; nt < 4; ++nt)
                        eacc[mi][nt] = __builtin_amdgcn_mfma_f32_16x16x32_f16(wa[mi][kc], bf[nt][kc], eacc[mi][nt], 0, 0, 0);
            float ps[4] = {0.f, 0.f, 0.f, 0.f};
#pragma unroll
            for (int mi = 0; mi < 2; ++mi)
#pragma unroll
                for (int nt = 0; nt < 4; ++nt)
#pragma unroll
                    for (int r = 0; r < 4; ++r) {
                        const float e = __expf(eacc[mi][nt][r]);
                        ps[nt] += e;
                        eacc[mi][nt][r] = e;
                    }
            float scn[4];
#pragma unroll
            for (int nt = 0; nt < 4; ++nt) {
                ps[nt] += __shfl_xor(ps[nt], 16);
                ps[nt] += __shfl_xor(ps[nt], 32);
                scn[nt] = SCALE_Q / ps[nt];
            }
#pragma unroll
            for (int mi = 0; mi < 2; ++mi) {
                const int d0 = (w * 2 + mi) * 16 + g * 4;
                const int sq = (((w * 2 + mi) * 4 + g) & 7) << 3;  // ((d0+r)>>2)&7, r<4
#pragma unroll
                for (int nt = 0; nt < 4; ++nt) {
                    const int jn = (nt * 16 + l15) ^ sq;
#pragma unroll
                    for (int r = 0; r < 4; ++r)
                        EQ[d0 + r][jn] = (_Float16)(eacc[mi][nt][r] * scn[nt]);
                }
            }
        }
        // k,v part (af per-mt from L2)
#pragma unroll
        for (int mt = 0; mt < 4; ++mt) {
            half8 afm[4];
#pragma unroll
            for (int kc = 0; kc < 4; ++kc)
                afm[kc] = *(const half8*)(Wb + (size_t)(128 + (w * 4 + mt) * 16 + l15) * 128 + kc * 32 + 8 * g);
            f32x4 a0 = (f32x4){0.f,0.f,0.f,0.f}, a1 = a0, a2 = a0, a3 = a0;
#pragma unroll
            for (int kc = 0; kc < 4; ++kc) {
                a0 = __builtin_amdgcn_mfma_f32_16x16x32_f16(afm[kc], bf[0][kc], a0, 0, 0, 0);
                a1 = __builtin_amdgcn_mfma_f32_16x16x32_f16(afm[kc], bf[1][kc], a1, 0, 0, 0);
                a2 = __builtin_amdgcn_mfma_f32_16x16x32_f16(afm[kc], bf[2][kc], a2, 0, 0, 0);
                a3 = __builtin_amdgcn_mfma_f32_16x16x32_f16(afm[kc], bf[3][kc], a3, 0, 0, 0);
            }
            const int lr0 = (w * 4 + mt) * 16 + g * 4;
            const int skv = (((w * 4 + mt) * 4 + g) & 7) << 3;
#pragma unroll
            for (int nt = 0; nt < 4; ++nt) {
                const f32x4 a = (nt == 0) ? a0 : (nt == 1) ? a1 : (nt == 2) ? a2 : a3;
                const int jn = (nt * 16 + l15) ^ skv;
                if (lr0 < 128) {
#pragma unroll
                    for (int r = 0; r < 4; ++r) KB[lr0 + r][jn] = (_Float16)__expf(a[r]);
                } else {
#pragma unroll
                    for (int r = 0; r < 4; ++r) VB[lr0 - 128 + r][jn] = (_Float16)a[r];
                }
            }
        }
        __syncthreads();   // (B) KB/VB/EQ ready; Xb reads done
        // stage tile it+1 into Xb (overlaps S/Z + copy-out)
        if (it < TILES - 1) {
#pragma unroll
            for (int cc = 0; cc < 8; ++cc) {
                const int c = c0 + 16 * cc;
                Xb[4 * j4 + 0][c ^ sxw] = (_Float16)xr[cc].x;
                Xb[4 * j4 + 1][c ^ sxw] = (_Float16)xr[cc].y;
                Xb[4 * j4 + 2][c ^ sxw] = (_Float16)xr[cc].z;
                Xb[4 * j4 + 3][c ^ sxw] = (_Float16)xr[cc].w;
            }
        }
        // S/Z accumulate
#pragma unroll
        for (int dm = 0; dm < 2; ++dm) {
            const int sr = ((4 * dm + (l15 >> 2)) & 7) << 3;
#pragma unroll
            for (int en = 0; en < 2; ++en)
#pragma unroll
                for (int kc = 0; kc < 2; ++kc) {
                    half8 ka = *(const half8*)(&KB[w * 32 + dm * 16 + l15][(kc * 32 + 8 * g) ^ sr]);
                    half8 vb = *(const half8*)(&VB[w * 32 + en * 16 + l15][(kc * 32 + 8 * g) ^ sr]);
                    sacc[dm][en] = __builtin_amdgcn_mfma_f32_16x16x32_f16(ka, vb, sacc[dm][en], 0, 0, 0);
                }
        }
        {
            const int zr = lane >> 1;
            const int sz = ((zr >> 2) & 7) << 3;
#pragma unroll
            for (int s8 = 0; s8 < 4; ++s8) {
                half8 hv = *(const half8*)(&KB[w * 32 + zr][((lane & 1) * 32 + 8 * s8) ^ sz]);
#pragma unroll
                for (int e = 0; e < 8; ++e) zpart += (float)hv[e];
            }
        }
        // Ê copy-out: full 128B rows -> 100% line efficiency
#pragma unroll
        for (int p = 0; p < 4; ++p) {
            const int idx = p * 256 + t, d = idx >> 3, c8 = idx & 7;
            half8 v = *(const half8*)(&EQ[d][(c8 * 8) ^ ((((d) >> 2) & 7) << 3)]);
            *(half8*)((_Float16*)(ybase + (size_t)(b * DIMC + d) * 131072) + j0 + c8 * 8) = v;
        }
    }
    {
        float zt = zpart + __shfl_xor(zpart, 1);
        if ((lane & 1) == 0) atomicAdd(&Z[(b * HEADS + w) * DHEAD + (lane >> 1)], zt);
    }
#pragma unroll
    for (int dm = 0; dm < 2; ++dm)
#pragma unroll
        for (int en = 0; en < 2; ++en)
#pragma unroll
            for (int r = 0; r < 4; ++r)
                atomicAdd(&S[((size_t)(b * HEADS + w) * DHEAD + dm * 16 + g * 4 + r) * DHEAD + en * 16 + l15],
                          sacc[dm][en][r]);
}

// ---------------- K2g: G[b][o][h*32+d] = sum_e wout[o][h*32+e]*S[b][h][d][e]/Z[b][h][d] (f16 -> ws) ----------------
// Overwrites the Wb region (dead after K1). One block per (h, b).
__global__ __launch_bounds__(256) void k2_g(const float* __restrict__ S, const float* __restrict__ Z,
                                            const float* __restrict__ wout, _Float16* __restrict__ G) {
    __shared__ float Sd[32][33];
    const int h = blockIdx.x, b = blockIdx.y;
    const int t = threadIdx.x;
    const float* Sb = S + (size_t)(b * HEADS + h) * 1024;
    const float* Zb = Z + (size_t)(b * HEADS + h) * 32;
    for (int i = t; i < 1024; i += 256) {
        int d = i >> 5;
        Sd[d][i & 31] = Sb[i] / Zb[d];
    }
    __syncthreads();
    const int o = t & 127, dh = (t >> 7) * 16;
    float wrow[32];
#pragma unroll
    for (int e = 0; e < 32; ++e) wrow[e] = wout[o * 128 + h * 32 + e];
    _Float16* Gb = G + (size_t)b * 16384;
#pragma unroll
    for (int dd = 0; dd < 16; ++dd) {
        const int d = dh + dd;
        float acc = 0.f;
#pragma unroll
        for (int e = 0; e < 32; ++e) acc = fmaf(wrow[e], Sd[d][e], acc);
        Gb[o * 128 + h * 32 + d] = (_Float16)acc;
    }
}

// ---------------- K3: streaming y = G @ Ê + b_out -> f16 stash + stats ----------------
__global__ __launch_bounds__(256, 2) void k3_main(const _Float16* __restrict__ G,
                                                  const float* __restrict__ b_out,
                                                  char* __restrict__ ybase,
                                                  float* __restrict__ St) {
    __shared__ _Float16 EB[64][136];  // Ê tile transposed: [j][d swizzled]
    __shared__ float red[8];
    const int t = threadIdx.x;
    const int lane = t & 63, w = t >> 6, g = lane >> 4, l15 = lane & 15;
    const int b = blockIdx.y;

    half8 ga[2][4];
    float bo[2][4];
    const _Float16* Gb = G + (size_t)b * 16384;
#pragma unroll
    for (int mi = 0; mi < 2; ++mi) {
        const int o = (w * 2 + mi) * 16 + l15;
#pragma unroll
        for (int kc = 0; kc < 4; ++kc)
            ga[mi][kc] = *(const half8*)(Gb + (size_t)o * 128 + kc * 32 + 8 * g);
#pragma unroll
        for (int r = 0; r < 4; ++r) bo[mi][r] = b_out[(w * 2 + mi) * 16 + g * 4 + r];
    }

    float ssum = 0.f, ssq = 0.f;
    half8 er[4];

    // stage tile 0
#pragma unroll
    for (int p = 0; p < 4; ++p) {
        const int idx = p * 256 + t, d = idx >> 3, jj = (idx & 7) * 8;
        er[p] = *(const half8*)((const _Float16*)(ybase + (size_t)(b * DIMC + d) * 131072) + blockIdx.x * 64 + jj);
    }
#pragma unroll
    for (int p = 0; p < 4; ++p) {
        const int idx = p * 256 + t, d = idx >> 3, jj = (idx & 7) * 8;
#pragma unroll
        for (int e = 0; e < 8; ++e) EB[jj + e][d ^ ((((jj + e) >> 2) & 7) << 3)] = er[p][e];
    }
    __syncthreads();

    for (int it = 0; it < TILES; ++it) {
        const int j0 = (blockIdx.x + GRIDX * it) * 64;
        if (it < TILES - 1) {
            const int j0n = (blockIdx.x + GRIDX * (it + 1)) * 64;
#pragma unroll
            for (int p = 0; p < 4; ++p) {
                const int idx = p * 256 + t, d = idx >> 3, jj = (idx & 7) * 8;
                er[p] = *(const half8*)((const _Float16*)(ybase + (size_t)(b * DIMC + d) * 131072) + j0n + jj);
            }
        }
        {
            half8 bf[4][4];
#pragma unroll
            for (int nt = 0; nt < 4; ++nt) {
                const int sb = ((4 * nt + (l15 >> 2)) & 7) << 3;
#pragma unroll
                for (int kc = 0; kc < 4; ++kc)
                    bf[nt][kc] = *(const half8*)(&EB[nt * 16 + l15][(kc * 32 + 8 * g) ^ sb]);
            }
#pragma unroll
            for (int mi = 0; mi < 2; ++mi) {
                const int o0 = (w * 2 + mi) * 16 + g * 4;
                f32x4 acc[4];
#pragma unroll
                for (int nt = 0; nt < 4; ++nt) acc[nt] = (f32x4){0.f, 0.f, 0.f, 0.f};
#pragma unroll
                for (int kc = 0; kc < 4; ++kc)
#pragma unroll
                    for (int nt = 0; nt < 4; ++nt)
                        acc[nt] = __builtin_amdgcn_mfma_f32_16x16x32_f16(ga[mi][kc], bf[nt][kc], acc[nt], 0, 0, 0);
#pragma unroll
                for (int r = 0; r < 4; ++r) {
                    _Float16* yrow = (_Float16*)(ybase + (size_t)(b * DIMC + o0 + r) * 131072 + 65536);
#pragma unroll
                    for (int nt = 0; nt < 4; ++nt) {
                        const float yv = acc[nt][r] + bo[mi][r];
                        ssum += yv;
                        ssq += yv * yv;
                        yrow[j0 + nt * 16 + l15] = (_Float16)yv;
                    }
                }
            }
        }
        __syncthreads();   // EB reads done
        if (it < TILES - 1) {
#pragma unroll
            for (int p = 0; p < 4; ++p) {
                const int idx = p * 256 + t, d = idx >> 3, jj = (idx & 7) * 8;
#pragma unroll
                for (int e = 0; e < 8; ++e) EB[jj + e][d ^ ((((jj + e) >> 2) & 7) << 3)] = er[p][e];
            }
        }
        __syncthreads();   // EB(next) ready
    }
#pragma unroll
    for (int m = 32; m; m >>= 1) { ssum += __shfl_xor(ssum, m); ssq += __shfl_xor(ssq, m); }
    if (lane == 0) { red[w] = ssum; red[4 + w] = ssq; }
    __syncthreads();
    if (t == 0) {
        atomicAdd(&St[b * 2 + 0], red[0] + red[1] + red[2] + red[3]);
        atomicAdd(&St[b * 2 + 1], red[4] + red[5] + red[6] + red[7]);
    }
}

// ---------------- K4: layernorm; read f16 stash (2nd half of own row), write f32 ----------------
__global__ __launch_bounds__(256) void k4_norm(float* __restrict__ out, const float* __restrict__ St,
                                               const float* __restrict__ gamma,
                                               const float* __restrict__ beta) {
    const int o = blockIdx.x;
    const int b = blockIdx.y;
    const int t = threadIdx.x;
    const size_t row = (size_t)b * DIMC + o;
    const float n = (float)DIMC * (float)NTOT;
    const float mean = St[b * 2] / n;
    const float var = St[b * 2 + 1] / n - mean * mean;
    const float rs = rsqrtf(var + 1e-5f);
    const float ga = gamma[o] * rs;
    const float be = beta[o];
    const half8* yh = (const half8*)((const char*)out + row * 131072 + 65536);
    half8 hbuf[16];
#pragma unroll
    for (int i = 0; i < 16; ++i) hbuf[i] = yh[i * 256 + t];
    __syncthreads();  // all reads before any f32 overwrite (stash lives in this row)
    float4* orow = (float4*)(out + row * NTOT);
#pragma unroll
    for (int i = 0; i < 16; ++i) {
        const int e4 = (i * 256 + t) * 2;
        float4 v0, v1;
        v0.x = ((float)hbuf[i][0] - mean) * ga + be;
        v0.y = ((float)hbuf[i][1] - mean) * ga + be;
        v0.z = ((float)hbuf[i][2] - mean) * ga + be;
        v0.w = ((float)hbuf[i][3] - mean) * ga + be;
        v1.x = ((float)hbuf[i][4] - mean) * ga + be;
        v1.y = ((float)hbuf[i][5] - mean) * ga + be;
        v1.z = ((float)hbuf[i][6] - mean) * ga + be;
        v1.w = ((float)hbuf[i][7] - mean) * ga + be;
        orow[e4] = v0;
        orow[e4 + 1] = v1;
    }
}

extern "C" void kernel_launch(void* const* d_in, const int* in_sizes, int n_in,
                              void* d_out, int out_size, void* d_ws, size_t ws_size,
                              hipStream_t stream) {
    const float* x     = (const float*)d_in[0];
    const float* wqkv  = (const float*)d_in[1];
    const float* wout  = (const float*)d_in[2];
    const float* b_out = (const float*)d_in[3];
    const float* gamma = (const float*)d_in[4];
    const float* beta  = (const float*)d_in[5];
    if (ws_size < WS_NEED) return;
    char* ws = (char*)d_ws;
    _Float16* Wb = (_Float16*)(ws + WS_WQKV);
    float* S  = (float*)(ws + WS_S);
    float* Z  = (float*)(ws + WS_Z);
    float* St = (float*)(ws + WS_ST);
    _Float16* G = (_Float16*)(ws + WS_GOFF);  // overwrites Wb region (dead after K1)

    k0_prep<<<325, 256, 0, stream>>>(wqkv, ws);
    k1_kv<<<dim3(GRIDX, 8), 256, 0, stream>>>(x, Wb, S, Z, (char*)d_out);
    k2_g<<<dim3(HEADS, 8), 256, 0, stream>>>(S, Z, wout, G);
    k3_main<<<dim3(GRIDX, 8), 256, 0, stream>>>(G, b_out, (char*)d_out, St);
    k4_norm<<<dim3(128, 8), 256, 0, stream>>>((float*)d_out, St, gamma, beta);
}

// Round 12
// 160.481 us; speedup vs baseline: 2.3150x; 1.5695x over previous
//
#include <hip/hip_runtime.h>

#define BATCH 8
#define DIMC 128
#define NTOT 32768
#define HEADS 4
#define DHEAD 32
#define SCALE_Q 0.17677669529663687f
#define GRIDX 64
#define TILES 8   // GRIDX * TILES * 64 == NTOT

typedef _Float16 half8  __attribute__((ext_vector_type(8)));
typedef _Float16 half4v __attribute__((ext_vector_type(4)));
typedef float    f32x4  __attribute__((ext_vector_type(4)));

// workspace byte offsets (all 16B aligned); ws_size >= 331840 proven in rounds 4-5
#define WS_WQKV 0        // _Float16[384*128] = 98304 B (dead after K1; G overwrites)
#define WS_S    98304    // float[8*4*32*32]  = 131072 B
#define WS_Z    229376   // float[8*4*32]     = 4096 B
#define WS_ST   233472   // float[16]
#define WS_GOFF 0        // G[b] f16 at ws + b*32768 (overwrites Wb region; Wb dead after K1)
#define WS_NEED 299072

// d_out row layout (each row 131072 B): LOWER half = Ê[b][d][j] f16 (K1 writes, K3 reads);
// UPPER half = y f16 stash (K3 writes, K4 reads row-locally then overwrites with f32).

// ---------------- K0: convert Wqkv to f16, zero accumulators ----------------
__global__ void k0_prep(const float* __restrict__ wqkv, char* __restrict__ ws) {
    int i = blockIdx.x * 256 + threadIdx.x;
    _Float16* Wb = (_Float16*)(ws + WS_WQKV);
    float* S  = (float*)(ws + WS_S);
    float* Z  = (float*)(ws + WS_Z);
    float* St = (float*)(ws + WS_ST);
    if (i < 49152) Wb[i] = (_Float16)wqkv[i];
    int j = i - 49152;
    if (j >= 0 && j < 32768) S[j] = 0.f;
    int k = j - 32768;
    if (k >= 0 && k < 1024) Z[k] = 0.f;
    int m = k - 1024;
    if (m >= 0 && m < 16) St[m] = 0.f;
}

// ---------------- K1: qkv projection; k,v -> S,Z; q -> Ê (softmax'd, f16, d_out lower halves) ----------------
// (256,1): hipcc splits the per-wave register budget ~50/50 arch/acc; at (256,2) the arch cap
// is 128 and this kernel's live set spills ~100 MB to scratch (R10/R11). LDS 66.5 KB caps
// occupancy at 2 blocks/CU anyway, so (256,1) costs nothing and lifts the cap.
__global__ __launch_bounds__(256, 1) void k1_kv(const float* __restrict__ x,
                                                const _Float16* __restrict__ Wb,
                                                float* __restrict__ S,
                                                float* __restrict__ Z,
                                                char* __restrict__ ybase) {
    __shared__ _Float16 Xb[64][136];   // x^T tile: [j][c swizzled]
    __shared__ _Float16 KB[128][64];   // exp(k): [h*32+d][j swizzled]
    __shared__ _Float16 VB[128][64];   // v:      [h*32+e][j swizzled]
    __shared__ _Float16 EQ[128][64];   // Ê:      [d][j swizzled]
    const int t = threadIdx.x;
    const int lane = t & 63, w = t >> 6, g = lane >> 4, l15 = lane & 15;
    const int b = blockIdx.y;

    // hoist only wa (32 VGPR); af loaded per-mt in-loop (register budget)
    half8 wa[2][4];
#pragma unroll
    for (int mi = 0; mi < 2; ++mi)
#pragma unroll
        for (int kc = 0; kc < 4; ++kc)
            wa[mi][kc] = *(const half8*)(Wb + (size_t)((w * 2 + mi) * 16 + l15) * 128 + kc * 32 + 8 * g);

    f32x4 sacc[2][2];
#pragma unroll
    for (int dm = 0; dm < 2; ++dm)
#pragma unroll
        for (int en = 0; en < 2; ++en) sacc[dm][en] = (f32x4){0.f, 0.f, 0.f, 0.f};
    float zpart = 0.f;

    const int j4 = t & 15, c0 = t >> 4;
    const int sxw = (j4 & 7) << 3;

    // prologue: load + stage tile 0
    float4 xr[8];
#pragma unroll
    for (int cc = 0; cc < 8; ++cc)
        xr[cc] = *(const float4*)(x + ((size_t)b * DIMC + c0 + 16 * cc) * NTOT + blockIdx.x * 64 + 4 * j4);
#pragma unroll
    for (int cc = 0; cc < 8; ++cc) {
        const int c = c0 + 16 * cc;
        Xb[4 * j4 + 0][c ^ sxw] = (_Float16)xr[cc].x;
        Xb[4 * j4 + 1][c ^ sxw] = (_Float16)xr[cc].y;
        Xb[4 * j4 + 2][c ^ sxw] = (_Float16)xr[cc].z;
        Xb[4 * j4 + 3][c ^ sxw] = (_Float16)xr[cc].w;
    }

    for (int it = 0; it < TILES; ++it) {
        const int j0 = (blockIdx.x + GRIDX * it) * 64;
        __syncthreads();   // (A) Xb ready; prev KB/VB/EQ reads done
        half8 bf[4][4];
#pragma unroll
        for (int nt = 0; nt < 4; ++nt) {
            const int sb = ((4 * nt + (l15 >> 2)) & 7) << 3;
#pragma unroll
            for (int kc = 0; kc < 4; ++kc)
                bf[nt][kc] = *(const half8*)(&Xb[nt * 16 + l15][(kc * 32 + 8 * g) ^ sb]);
        }
        // q part: E=exp(q), per-column colsum over head w, Ê = E*SCALE/colsum -> EQ LDS
        {
            f32x4 eacc[2][4];
#pragma unroll
            for (int mi = 0; mi < 2; ++mi)
#pragma unroll
                for (int nt = 0; nt < 4; ++nt) eacc[mi][nt] = (f32x4){0.f, 0.f, 0.f, 0.f};
#pragma unroll
            for (int mi = 0; mi < 2; ++mi)
#pragma unroll
                for (int kc = 0; kc < 4; ++kc)
#pragma unroll
                    for (int nt = 0; nt < 4; ++nt)
                        eacc[mi][nt] = __builtin_amdgcn_mfma_f32_16x16x32_f16(wa[mi][kc], bf[nt][kc], eacc[mi][nt], 0, 0, 0);
            float ps[4] = {0.f, 0.f, 0.f, 0.f};
#pragma unroll
            for (int mi = 0; mi < 2; ++mi)
#pragma unroll
                for (int nt = 0; nt < 4; ++nt)
#pragma unroll
                    for (int r = 0; r < 4; ++r) {
                        const float e = __expf(eacc[mi][nt][r]);
                        ps[nt] += e;
                        eacc[mi][nt][r] = e;
                    }
            float scn[4];
#pragma unroll
            for (int nt = 0; nt < 4; ++nt) {
                ps[nt] += __shfl_xor(ps[nt], 16);
                ps[nt] += __shfl_xor(ps[nt], 32);
                scn[nt] = SCALE_Q / ps[nt];
            }
#pragma unroll
            for (int mi = 0; mi < 2; ++mi) {
                const int d0 = (w * 2 + mi) * 16 + g * 4;
                const int sq = (((w * 2 + mi) * 4 + g) & 7) << 3;  // ((d0+r)>>2)&7, r<4
#pragma unroll
                for (int nt = 0; nt < 4; ++nt) {
                    const int jn = (nt * 16 + l15) ^ sq;
#pragma unroll
                    for (int r = 0; r < 4; ++r)
                        EQ[d0 + r][jn] = (_Float16)(eacc[mi][nt][r] * scn[nt]);
                }
            }
        }
        // next-tile global loads issued AFTER the q-part (keeps xr out of the peak live set);
        // kv + S/Z phases below cover the latency before the stage-write.
        if (it < TILES - 1) {
            const int j0n = (blockIdx.x + GRIDX * (it + 1)) * 64;
#pragma unroll
            for (int cc = 0; cc < 8; ++cc)
                xr[cc] = *(const float4*)(x + ((size_t)b * DIMC + c0 + 16 * cc) * NTOT + j0n + 4 * j4);
        }
        // k,v part (af per-mt from L2)
#pragma unroll
        for (int mt = 0; mt < 4; ++mt) {
            half8 afm[4];
#pragma unroll
            for (int kc = 0; kc < 4; ++kc)
                afm[kc] = *(const half8*)(Wb + (size_t)(128 + (w * 4 + mt) * 16 + l15) * 128 + kc * 32 + 8 * g);
            f32x4 a0 = (f32x4){0.f,0.f,0.f,0.f}, a1 = a0, a2 = a0, a3 = a0;
#pragma unroll
            for (int kc = 0; kc < 4; ++kc) {
                a0 = __builtin_amdgcn_mfma_f32_16x16x32_f16(afm[kc], bf[0][kc], a0, 0, 0, 0);
                a1 = __builtin_amdgcn_mfma_f32_16x16x32_f16(afm[kc], bf[1][kc], a1, 0, 0, 0);
                a2 = __builtin_amdgcn_mfma_f32_16x16x32_f16(afm[kc], bf[2][kc], a2, 0, 0, 0);
                a3 = __builtin_amdgcn_mfma_f32_16x16x32_f16(afm[kc], bf[3][kc], a3, 0, 0, 0);
            }
            const int lr0 = (w * 4 + mt) * 16 + g * 4;
            const int skv = (((w * 4 + mt) * 4 + g) & 7) << 3;
#pragma unroll
            for (int nt = 0; nt < 4; ++nt) {
                const f32x4 a = (nt == 0) ? a0 : (nt == 1) ? a1 : (nt == 2) ? a2 : a3;
                const int jn = (nt * 16 + l15) ^ skv;
                if (lr0 < 128) {
#pragma unroll
                    for (int r = 0; r < 4; ++r) KB[lr0 + r][jn] = (_Float16)__expf(a[r]);
                } else {
#pragma unroll
                    for (int r = 0; r < 4; ++r) VB[lr0 - 128 + r][jn] = (_Float16)a[r];
                }
            }
        }
        __syncthreads();   // (B) KB/VB/EQ ready; Xb reads done
        // stage tile it+1 into Xb (overlaps S/Z + copy-out)
        if (it < TILES - 1) {
#pragma unroll
            for (int cc = 0; cc < 8; ++cc) {
                const int c = c0 + 16 * cc;
                Xb[4 * j4 + 0][c ^ sxw] = (_Float16)xr[cc].x;
                Xb[4 * j4 + 1][c ^ sxw] = (_Float16)xr[cc].y;
                Xb[4 * j4 + 2][c ^ sxw] = (_Float16)xr[cc].z;
                Xb[4 * j4 + 3][c ^ sxw] = (_Float16)xr[cc].w;
            }
        }
        // S/Z accumulate
#pragma unroll
        for (int dm = 0; dm < 2; ++dm) {
            const int sr = ((4 * dm + (l15 >> 2)) & 7) << 3;
#pragma unroll
            for (int en = 0; en < 2; ++en)
#pragma unroll
                for (int kc = 0; kc < 2; ++kc) {
                    half8 ka = *(const half8*)(&KB[w * 32 + dm * 16 + l15][(kc * 32 + 8 * g) ^ sr]);
                    half8 vb = *(const half8*)(&VB[w * 32 + en * 16 + l15][(kc * 32 + 8 * g) ^ sr]);
                    sacc[dm][en] = __builtin_amdgcn_mfma_f32_16x16x32_f16(ka, vb, sacc[dm][en], 0, 0, 0);
                }
        }
        {
            const int zr = lane >> 1;
            const int sz = ((zr >> 2) & 7) << 3;
#pragma unroll
            for (int s8 = 0; s8 < 4; ++s8) {
                half8 hv = *(const half8*)(&KB[w * 32 + zr][((lane & 1) * 32 + 8 * s8) ^ sz]);
#pragma unroll
                for (int e = 0; e < 8; ++e) zpart += (float)hv[e];
            }
        }
        // Ê copy-out: full 128B rows -> 100% line efficiency
#pragma unroll
        for (int p = 0; p < 4; ++p) {
            const int idx = p * 256 + t, d = idx >> 3, c8 = idx & 7;
            half8 v = *(const half8*)(&EQ[d][(c8 * 8) ^ ((((d) >> 2) & 7) << 3)]);
            *(half8*)((_Float16*)(ybase + (size_t)(b * DIMC + d) * 131072) + j0 + c8 * 8) = v;
        }
    }
    {
        float zt = zpart + __shfl_xor(zpart, 1);
        if ((lane & 1) == 0) atomicAdd(&Z[(b * HEADS + w) * DHEAD + (lane >> 1)], zt);
    }
#pragma unroll
    for (int dm = 0; dm < 2; ++dm)
#pragma unroll
        for (int en = 0; en < 2; ++en)
#pragma unroll
            for (int r = 0; r < 4; ++r)
                atomicAdd(&S[((size_t)(b * HEADS + w) * DHEAD + dm * 16 + g * 4 + r) * DHEAD + en * 16 + l15],
                          sacc[dm][en][r]);
}

// ---------------- K2g: G[b][o][h*32+d] = sum_e wout[o][h*32+e]*S[b][h][d][e]/Z[b][h][d] (f16 -> ws) ----------------
__global__ __launch_bounds__(256) void k2_g(const float* __restrict__ S, const float* __restrict__ Z,
                                            const float* __restrict__ wout, _Float16* __restrict__ G) {
    __shared__ float Sd[32][33];
    const int h = blockIdx.x, b = blockIdx.y;
    const int t = threadIdx.x;
    const float* Sb = S + (size_t)(b * HEADS + h) * 1024;
    const float* Zb = Z + (size_t)(b * HEADS + h) * 32;
    for (int i = t; i < 1024; i += 256) {
        int d = i >> 5;
        Sd[d][i & 31] = Sb[i] / Zb[d];
    }
    __syncthreads();
    const int o = t & 127, dh = (t >> 7) * 16;
    float wrow[32];
#pragma unroll
    for (int e = 0; e < 32; ++e) wrow[e] = wout[o * 128 + h * 32 + e];
    _Float16* Gb = G + (size_t)b * 16384;
#pragma unroll
    for (int dd = 0; dd < 16; ++dd) {
        const int d = dh + dd;
        float acc = 0.f;
#pragma unroll
        for (int e = 0; e < 32; ++e) acc = fmaf(wrow[e], Sd[d][e], acc);
        Gb[o * 128 + h * 32 + d] = (_Float16)acc;
    }
}

// ---------------- K3: streaming y = G @ Ê + b_out -> f16 stash + stats ----------------
__global__ __launch_bounds__(256, 2) void k3_main(const _Float16* __restrict__ G,
                                                  const float* __restrict__ b_out,
                                                  char* __restrict__ ybase,
                                                  float* __restrict__ St) {
    __shared__ _Float16 EB[64][136];  // Ê tile transposed: [j][d swizzled]
    __shared__ float red[8];
    const int t = threadIdx.x;
    const int lane = t & 63, w = t >> 6, g = lane >> 4, l15 = lane & 15;
    const int b = blockIdx.y;

    half8 ga[2][4];
    float bo[2][4];
    const _Float16* Gb = G + (size_t)b * 16384;
#pragma unroll
    for (int mi = 0; mi < 2; ++mi) {
        const int o = (w * 2 + mi) * 16 + l15;
#pragma unroll
        for (int kc = 0; kc < 4; ++kc)
            ga[mi][kc] = *(const half8*)(Gb + (size_t)o * 128 + kc * 32 + 8 * g);
#pragma unroll
        for (int r = 0; r < 4; ++r) bo[mi][r] = b_out[(w * 2 + mi) * 16 + g * 4 + r];
    }

    float ssum = 0.f, ssq = 0.f;
    half8 er[4];

    // stage tile 0
#pragma unroll
    for (int p = 0; p < 4; ++p) {
        const int idx = p * 256 + t, d = idx >> 3, jj = (idx & 7) * 8;
        er[p] = *(const half8*)((const _Float16*)(ybase + (size_t)(b * DIMC + d) * 131072) + blockIdx.x * 64 + jj);
    }
#pragma unroll
    for (int p = 0; p < 4; ++p) {
        const int idx = p * 256 + t, d = idx >> 3, jj = (idx & 7) * 8;
#pragma unroll
        for (int e = 0; e < 8; ++e) EB[jj + e][d ^ ((((jj + e) >> 2) & 7) << 3)] = er[p][e];
    }
    __syncthreads();

    for (int it = 0; it < TILES; ++it) {
        const int j0 = (blockIdx.x + GRIDX * it) * 64;
        if (it < TILES - 1) {
            const int j0n = (blockIdx.x + GRIDX * (it + 1)) * 64;
#pragma unroll
            for (int p = 0; p < 4; ++p) {
                const int idx = p * 256 + t, d = idx >> 3, jj = (idx & 7) * 8;
                er[p] = *(const half8*)((const _Float16*)(ybase + (size_t)(b * DIMC + d) * 131072) + j0n + jj);
            }
        }
        {
            half8 bf[4][4];
#pragma unroll
            for (int nt = 0; nt < 4; ++nt) {
                const int sb = ((4 * nt + (l15 >> 2)) & 7) << 3;
#pragma unroll
                for (int kc = 0; kc < 4; ++kc)
                    bf[nt][kc] = *(const half8*)(&EB[nt * 16 + l15][(kc * 32 + 8 * g) ^ sb]);
            }
#pragma unroll
            for (int mi = 0; mi < 2; ++mi) {
                const int o0 = (w * 2 + mi) * 16 + g * 4;
                f32x4 acc[4];
#pragma unroll
                for (int nt = 0; nt < 4; ++nt) acc[nt] = (f32x4){0.f, 0.f, 0.f, 0.f};
#pragma unroll
                for (int kc = 0; kc < 4; ++kc)
#pragma unroll
                    for (int nt = 0; nt < 4; ++nt)
                        acc[nt] = __builtin_amdgcn_mfma_f32_16x16x32_f16(ga[mi][kc], bf[nt][kc], acc[nt], 0, 0, 0);
#pragma unroll
                for (int r = 0; r < 4; ++r) {
                    _Float16* yrow = (_Float16*)(ybase + (size_t)(b * DIMC + o0 + r) * 131072 + 65536);
#pragma unroll
                    for (int nt = 0; nt < 4; ++nt) {
                        const float yv = acc[nt][r] + bo[mi][r];
                        ssum += yv;
                        ssq += yv * yv;
                        yrow[j0 + nt * 16 + l15] = (_Float16)yv;
                    }
                }
            }
        }
        __syncthreads();   // EB reads done
        if (it < TILES - 1) {
#pragma unroll
            for (int p = 0; p < 4; ++p) {
                const int idx = p * 256 + t, d = idx >> 3, jj = (idx & 7) * 8;
#pragma unroll
                for (int e = 0; e < 8; ++e) EB[jj + e][d ^ ((((jj + e) >> 2) & 7) << 3)] = er[p][e];
            }
        }
        __syncthreads();   // EB(next) ready
    }
#pragma unroll
    for (int m = 32; m; m >>= 1) { ssum += __shfl_xor(ssum, m); ssq += __shfl_xor(ssq, m); }
    if (lane == 0) { red[w] = ssum; red[4 + w] = ssq; }
    __syncthreads();
    if (t == 0) {
        atomicAdd(&St[b * 2 + 0], red[0] + red[1] + red[2] + red[3]);
        atomicAdd(&St[b * 2 + 1], red[4] + red[5] + red[6] + red[7]);
    }
}

// ---------------- K4: layernorm; read f16 stash (2nd half of own row), write f32 ----------------
__global__ __launch_bounds__(256) void k4_norm(float* __restrict__ out, const float* __restrict__ St,
                                               const float* __restrict__ gamma,
                                               const float* __restrict__ beta) {
    const int o = blockIdx.x;
    const int b = blockIdx.y;
    const int t = threadIdx.x;
    const size_t row = (size_t)b * DIMC + o;
    const float n = (float)DIMC * (float)NTOT;
    const float mean = St[b * 2] / n;
    const float var = St[b * 2 + 1] / n - mean * mean;
    const float rs = rsqrtf(var + 1e-5f);
    const float ga = gamma[o] * rs;
    const float be = beta[o];
    const half8* yh = (const half8*)((const char*)out + row * 131072 + 65536);
    half8 hbuf[16];
#pragma unroll
    for (int i = 0; i < 16; ++i) hbuf[i] = yh[i * 256 + t];
    __syncthreads();  // all reads before any f32 overwrite (stash lives in this row)
    float4* orow = (float4*)(out + row * NTOT);
#pragma unroll
    for (int i = 0; i < 16; ++i) {
        const int e4 = (i * 256 + t) * 2;
        float4 v0, v1;
        v0.x = ((float)hbuf[i][0] - mean) * ga + be;
        v0.y = ((float)hbuf[i][1] - mean) * ga + be;
        v0.z = ((float)hbuf[i][2] - mean) * ga + be;
        v0.w = ((float)hbuf[i][3] - mean) * ga + be;
        v1.x = ((float)hbuf[i][4] - mean) * ga + be;
        v1.y = ((float)hbuf[i][5] - mean) * ga + be;
        v1.z = ((float)hbuf[i][6] - mean) * ga + be;
        v1.w = ((float)hbuf[i][7] - mean) * ga + be;
        orow[e4] = v0;
        orow[e4 + 1] = v1;
    }
}

extern "C" void kernel_launch(void* const* d_in, const int* in_sizes, int n_in,
                              void* d_out, int out_size, void* d_ws, size_t ws_size,
                              hipStream_t stream) {
    const float* x     = (const float*)d_in[0];
    const float* wqkv  = (const float*)d_in[1];
    const float* wout  = (const float*)d_in[2];
    const float* b_out = (const float*)d_in[3];
    const float* gamma = (const float*)d_in[4];
    const float* beta  = (const float*)d_in[5];
    if (ws_size < WS_NEED) return;
    char* ws = (char*)d_ws;
    _Float16* Wb = (_Float16*)(ws + WS_WQKV);
    float* S  = (float*)(ws + WS_S);
    float* Z  = (float*)(ws + WS_Z);
    float* St = (float*)(ws + WS_ST);
    _Float16* G = (_Float16*)(ws + WS_GOFF);  // overwrites Wb region (dead after K1)

    k0_prep<<<325, 256, 0, stream>>>(wqkv, ws);
    k1_kv<<<dim3(GRIDX, 8), 256, 0, stream>>>(x, Wb, S, Z, (char*)d_out);
    k2_g<<<dim3(HEADS, 8), 256, 0, stream>>>(S, Z, wout, G);
    k3_main<<<dim3(GRIDX, 8), 256, 0, stream>>>(G, b_out, (char*)d_out, St);
    k4_norm<<<dim3(128, 8), 256, 0, stream>>>((float*)d_out, St, gamma, beta);
}

// Round 13
// 159.106 us; speedup vs baseline: 2.3351x; 1.0086x over previous
//
#include <hip/hip_runtime.h>

#define BATCH 8
#define DIMC 128
#define NTOT 32768
#define HEADS 4
#define DHEAD 32
#define SCALE_Q 0.17677669529663687f
#define GRIDX 64
#define TILES 8   // GRIDX * TILES * 64 == NTOT

typedef _Float16 half8  __attribute__((ext_vector_type(8)));
typedef _Float16 half4v __attribute__((ext_vector_type(4)));
typedef float    f32x4  __attribute__((ext_vector_type(4)));

// workspace byte offsets (all 16B aligned)
#define WS_WQKV 0        // _Float16[384*128] = 98304 B (dead after K1; G overwrites)
#define WS_S    98304    // float[8*4*32*32]  = 131072 B
#define WS_Z    229376   // float[8*4*32]     = 4096 B
#define WS_ST   233472   // float[16]
#define WS_GOFF 0        // G[b] f16 at ws + b*32768 (overwrites Wb region; Wb dead after K1)
#define WS_NEED 299072

// d_out row layout (each row 131072 B): LOWER half = Ê[b][d][j] f16 (K1 writes, K3 reads);
// UPPER half = y f16 stash (K3 writes, K4 reads row-locally then overwrites with f32).

// ---------------- K0: convert Wqkv to f16, zero accumulators ----------------
__global__ void k0_prep(const float* __restrict__ wqkv, char* __restrict__ ws) {
    int i = blockIdx.x * 256 + threadIdx.x;
    _Float16* Wb = (_Float16*)(ws + WS_WQKV);
    float* S  = (float*)(ws + WS_S);
    float* Z  = (float*)(ws + WS_Z);
    float* St = (float*)(ws + WS_ST);
    if (i < 49152) Wb[i] = (_Float16)wqkv[i];
    int j = i - 49152;
    if (j >= 0 && j < 32768) S[j] = 0.f;
    int k = j - 32768;
    if (k >= 0 && k < 1024) Z[k] = 0.f;
    int m = k - 1024;
    if (m >= 0 && m < 16) St[m] = 0.f;
}

// ---------------- K1: qkv projection; k,v -> S,Z; q -> Ê (softmax'd, f16, d_out lower halves) ----------------
// kv-GEMM uses SWAPPED mfma operands (D[m=j][n=row]) so KB/VB writes are half4-vectorized.
// Z computed via MFMA with a ones B-frag. vb read-swizzle fixed to en-based (was dm-based:
// paired E[d][j] with V[e][j^32] on off-diagonal quadrants — ~0.6% S error since R2).
__global__ __launch_bounds__(256, 1) void k1_kv(const float* __restrict__ x,
                                                const _Float16* __restrict__ Wb,
                                                float* __restrict__ S,
                                                float* __restrict__ Z,
                                                char* __restrict__ ybase) {
    __shared__ _Float16 Xb[64][136];   // x^T tile: [j][c swizzled]
    __shared__ _Float16 KB[128][64];   // exp(k): [h*32+d][j swizzled]
    __shared__ _Float16 VB[128][64];   // v:      [h*32+e][j swizzled]
    __shared__ _Float16 EQ[128][64];   // Ê:      [d][j swizzled]
    const int t = threadIdx.x;
    const int lane = t & 63, w = t >> 6, g = lane >> 4, l15 = lane & 15;
    const int b = blockIdx.y;

    half8 wa[2][4];
#pragma unroll
    for (int mi = 0; mi < 2; ++mi)
#pragma unroll
        for (int kc = 0; kc < 4; ++kc)
            wa[mi][kc] = *(const half8*)(Wb + (size_t)((w * 2 + mi) * 16 + l15) * 128 + kc * 32 + 8 * g);

    half8 vone;
#pragma unroll
    for (int i = 0; i < 8; ++i) vone[i] = (_Float16)1.0f;

    f32x4 sacc[2][2];
#pragma unroll
    for (int dm = 0; dm < 2; ++dm)
#pragma unroll
        for (int en = 0; en < 2; ++en) sacc[dm][en] = (f32x4){0.f, 0.f, 0.f, 0.f};
    f32x4 zacc[2];
    zacc[0] = (f32x4){0.f, 0.f, 0.f, 0.f};
    zacc[1] = (f32x4){0.f, 0.f, 0.f, 0.f};

    const int j4 = t & 15, c0 = t >> 4;
    const int sxw = (j4 & 7) << 3;

    // prologue: load + stage tile 0
    float4 xr[8];
#pragma unroll
    for (int cc = 0; cc < 8; ++cc)
        xr[cc] = *(const float4*)(x + ((size_t)b * DIMC + c0 + 16 * cc) * NTOT + blockIdx.x * 64 + 4 * j4);
#pragma unroll
    for (int cc = 0; cc < 8; ++cc) {
        const int c = c0 + 16 * cc;
        Xb[4 * j4 + 0][c ^ sxw] = (_Float16)xr[cc].x;
        Xb[4 * j4 + 1][c ^ sxw] = (_Float16)xr[cc].y;
        Xb[4 * j4 + 2][c ^ sxw] = (_Float16)xr[cc].z;
        Xb[4 * j4 + 3][c ^ sxw] = (_Float16)xr[cc].w;
    }

    for (int it = 0; it < TILES; ++it) {
        const int j0 = (blockIdx.x + GRIDX * it) * 64;
        __syncthreads();   // (A) Xb ready; prev KB/VB/EQ reads done
        half8 bf[4][4];
#pragma unroll
        for (int nt = 0; nt < 4; ++nt) {
            const int sb = ((4 * nt + (l15 >> 2)) & 7) << 3;
#pragma unroll
            for (int kc = 0; kc < 4; ++kc)
                bf[nt][kc] = *(const half8*)(&Xb[nt * 16 + l15][(kc * 32 + 8 * g) ^ sb]);
        }
        // q part: E=exp(q), per-column colsum over head w, Ê = E*SCALE/colsum -> EQ LDS
        {
            f32x4 eacc[2][4];
#pragma unroll
            for (int mi = 0; mi < 2; ++mi)
#pragma unroll
                for (int nt = 0; nt < 4; ++nt) eacc[mi][nt] = (f32x4){0.f, 0.f, 0.f, 0.f};
#pragma unroll
            for (int mi = 0; mi < 2; ++mi)
#pragma unroll
                for (int kc = 0; kc < 4; ++kc)
#pragma unroll
                    for (int nt = 0; nt < 4; ++nt)
                        eacc[mi][nt] = __builtin_amdgcn_mfma_f32_16x16x32_f16(wa[mi][kc], bf[nt][kc], eacc[mi][nt], 0, 0, 0);
            float ps[4] = {0.f, 0.f, 0.f, 0.f};
#pragma unroll
            for (int mi = 0; mi < 2; ++mi)
#pragma unroll
                for (int nt = 0; nt < 4; ++nt)
#pragma unroll
                    for (int r = 0; r < 4; ++r) {
                        const float e = __expf(eacc[mi][nt][r]);
                        ps[nt] += e;
                        eacc[mi][nt][r] = e;
                    }
            float scn[4];
#pragma unroll
            for (int nt = 0; nt < 4; ++nt) {
                ps[nt] += __shfl_xor(ps[nt], 16);
                ps[nt] += __shfl_xor(ps[nt], 32);
                scn[nt] = SCALE_Q / ps[nt];
            }
#pragma unroll
            for (int mi = 0; mi < 2; ++mi) {
                const int d0 = (w * 2 + mi) * 16 + g * 4;
                const int sq = (((w * 2 + mi) * 4 + g) & 7) << 3;
#pragma unroll
                for (int nt = 0; nt < 4; ++nt) {
                    const int jn = (nt * 16 + l15) ^ sq;
#pragma unroll
                    for (int r = 0; r < 4; ++r)
                        EQ[d0 + r][jn] = (_Float16)(eacc[mi][nt][r] * scn[nt]);
                }
            }
        }
        // next-tile global loads issued AFTER the q-part (keeps xr out of the peak live set)
        if (it < TILES - 1) {
            const int j0n = (blockIdx.x + GRIDX * (it + 1)) * 64;
#pragma unroll
            for (int cc = 0; cc < 8; ++cc)
                xr[cc] = *(const float4*)(x + ((size_t)b * DIMC + c0 + 16 * cc) * NTOT + j0n + 4 * j4);
        }
        // k,v part — SWAPPED operands: a[jt] holds D[m=j][n=row]; lane = 4 consecutive j at one row
#pragma unroll
        for (int mt = 0; mt < 4; ++mt) {
            half8 afm[4];
#pragma unroll
            for (int kc = 0; kc < 4; ++kc)
                afm[kc] = *(const half8*)(Wb + (size_t)(128 + (w * 4 + mt) * 16 + l15) * 128 + kc * 32 + 8 * g);
            f32x4 a0 = (f32x4){0.f,0.f,0.f,0.f}, a1 = a0, a2 = a0, a3 = a0;
#pragma unroll
            for (int kc = 0; kc < 4; ++kc) {
                a0 = __builtin_amdgcn_mfma_f32_16x16x32_f16(bf[0][kc], afm[kc], a0, 0, 0, 0);
                a1 = __builtin_amdgcn_mfma_f32_16x16x32_f16(bf[1][kc], afm[kc], a1, 0, 0, 0);
                a2 = __builtin_amdgcn_mfma_f32_16x16x32_f16(bf[2][kc], afm[kc], a2, 0, 0, 0);
                a3 = __builtin_amdgcn_mfma_f32_16x16x32_f16(bf[3][kc], afm[kc], a3, 0, 0, 0);
            }
            const int row16 = (w * 4 + mt) * 16;                 // tile base (uniform)
            const int sk = ((mt * 4 + (l15 >> 2)) & 7) << 3;     // ((row>>2)&7)<<3, row=row16+l15
            if (row16 < 128) {
#pragma unroll
                for (int jt = 0; jt < 4; ++jt) {
                    const f32x4 a = (jt == 0) ? a0 : (jt == 1) ? a1 : (jt == 2) ? a2 : a3;
                    half4v p;
#pragma unroll
                    for (int r = 0; r < 4; ++r) p[r] = (_Float16)__expf(a[r]);
                    *(half4v*)(&KB[row16 + l15][(jt * 16 + g * 4) ^ sk]) = p;
                }
            } else {
#pragma unroll
                for (int jt = 0; jt < 4; ++jt) {
                    const f32x4 a = (jt == 0) ? a0 : (jt == 1) ? a1 : (jt == 2) ? a2 : a3;
                    half4v p;
#pragma unroll
                    for (int r = 0; r < 4; ++r) p[r] = (_Float16)a[r];
                    *(half4v*)(&VB[row16 - 128 + l15][(jt * 16 + g * 4) ^ sk]) = p;
                }
            }
        }
        __syncthreads();   // (B) KB/VB/EQ ready; Xb reads done
        // stage tile it+1 into Xb (overlaps S/Z + copy-out)
        if (it < TILES - 1) {
#pragma unroll
            for (int cc = 0; cc < 8; ++cc) {
                const int c = c0 + 16 * cc;
                Xb[4 * j4 + 0][c ^ sxw] = (_Float16)xr[cc].x;
                Xb[4 * j4 + 1][c ^ sxw] = (_Float16)xr[cc].y;
                Xb[4 * j4 + 2][c ^ sxw] = (_Float16)xr[cc].z;
                Xb[4 * j4 + 3][c ^ sxw] = (_Float16)xr[cc].w;
            }
        }
        // S/Z accumulate (Z via ones-MFMA; vb swizzle en-based — the fix)
#pragma unroll
        for (int dm = 0; dm < 2; ++dm) {
            const int sr = ((4 * dm + (l15 >> 2)) & 7) << 3;
            half8 ka0 = *(const half8*)(&KB[w * 32 + dm * 16 + l15][(8 * g) ^ sr]);
            half8 ka1 = *(const half8*)(&KB[w * 32 + dm * 16 + l15][(32 + 8 * g) ^ sr]);
            zacc[dm] = __builtin_amdgcn_mfma_f32_16x16x32_f16(ka0, vone, zacc[dm], 0, 0, 0);
            zacc[dm] = __builtin_amdgcn_mfma_f32_16x16x32_f16(ka1, vone, zacc[dm], 0, 0, 0);
#pragma unroll
            for (int en = 0; en < 2; ++en) {
                const int se = ((4 * en + (l15 >> 2)) & 7) << 3;
                half8 vb0 = *(const half8*)(&VB[w * 32 + en * 16 + l15][(8 * g) ^ se]);
                half8 vb1 = *(const half8*)(&VB[w * 32 + en * 16 + l15][(32 + 8 * g) ^ se]);
                sacc[dm][en] = __builtin_amdgcn_mfma_f32_16x16x32_f16(ka0, vb0, sacc[dm][en], 0, 0, 0);
                sacc[dm][en] = __builtin_amdgcn_mfma_f32_16x16x32_f16(ka1, vb1, sacc[dm][en], 0, 0, 0);
            }
        }
        // Ê copy-out: full 128B rows -> 100% line efficiency
#pragma unroll
        for (int p = 0; p < 4; ++p) {
            const int idx = p * 256 + t, d = idx >> 3, c8 = idx & 7;
            half8 v = *(const half8*)(&EQ[d][(c8 * 8) ^ ((((d) >> 2) & 7) << 3)]);
            *(half8*)((_Float16*)(ybase + (size_t)(b * DIMC + d) * 131072) + j0 + c8 * 8) = v;
        }
    }
    // flush Z (every column of zacc holds Z[d]; take l15==0 lanes)
    if (l15 == 0) {
#pragma unroll
        for (int dm = 0; dm < 2; ++dm)
#pragma unroll
            for (int r = 0; r < 4; ++r)
                atomicAdd(&Z[(b * HEADS + w) * DHEAD + dm * 16 + g * 4 + r], zacc[dm][r]);
    }
#pragma unroll
    for (int dm = 0; dm < 2; ++dm)
#pragma unroll
        for (int en = 0; en < 2; ++en)
#pragma unroll
            for (int r = 0; r < 4; ++r)
                atomicAdd(&S[((size_t)(b * HEADS + w) * DHEAD + dm * 16 + g * 4 + r) * DHEAD + en * 16 + l15],
                          sacc[dm][en][r]);
}

// ---------------- K2g: G[b][o][h*32+d] = sum_e wout[o][h*32+e]*S[b][h][d][e]/Z[b][h][d] (f16 -> ws) ----------------
__global__ __launch_bounds__(256) void k2_g(const float* __restrict__ S, const float* __restrict__ Z,
                                            const float* __restrict__ wout, _Float16* __restrict__ G) {
    __shared__ float Sd[32][33];
    const int h = blockIdx.x, b = blockIdx.y;
    const int t = threadIdx.x;
    const float* Sb = S + (size_t)(b * HEADS + h) * 1024;
    const float* Zb = Z + (size_t)(b * HEADS + h) * 32;
    for (int i = t; i < 1024; i += 256) {
        int d = i >> 5;
        Sd[d][i & 31] = Sb[i] / Zb[d];
    }
    __syncthreads();
    const int o = t & 127, dh = (t >> 7) * 16;
    float wrow[32];
#pragma unroll
    for (int e = 0; e < 32; ++e) wrow[e] = wout[o * 128 + h * 32 + e];
    _Float16* Gb = G + (size_t)b * 16384;
#pragma unroll
    for (int dd = 0; dd < 16; ++dd) {
        const int d = dh + dd;
        float acc = 0.f;
#pragma unroll
        for (int e = 0; e < 32; ++e) acc = fmaf(wrow[e], Sd[d][e], acc);
        Gb[o * 128 + h * 32 + d] = (_Float16)acc;
    }
}

// ---------------- K3: streaming y = G @ Ê + b_out -> f16 stash + stats ----------------
__global__ __launch_bounds__(256, 2) void k3_main(const _Float16* __restrict__ G,
                                                  const float* __restrict__ b_out,
                                                  char* __restrict__ ybase,
                                                  float* __restrict__ St) {
    __shared__ _Float16 EB[64][136];  // Ê tile transposed: [j][d swizzled]
    __shared__ float red[8];
    const int t = threadIdx.x;
    const int lane = t & 63, w = t >> 6, g = lane >> 4, l15 = lane & 15;
    const int b = blockIdx.y;

    half8 ga[2][4];
    float bo[2][4];
    const _Float16* Gb = G + (size_t)b * 16384;
#pragma unroll
    for (int mi = 0; mi < 2; ++mi) {
        const int o = (w * 2 + mi) * 16 + l15;
#pragma unroll
        for (int kc = 0; kc < 4; ++kc)
            ga[mi][kc] = *(const half8*)(Gb + (size_t)o * 128 + kc * 32 + 8 * g);
#pragma unroll
        for (int r = 0; r < 4; ++r) bo[mi][r] = b_out[(w * 2 + mi) * 16 + g * 4 + r];
    }

    float ssum = 0.f, ssq = 0.f;
    half8 er[4];

    // stage tile 0
#pragma unroll
    for (int p = 0; p < 4; ++p) {
        const int idx = p * 256 + t, d = idx >> 3, jj = (idx & 7) * 8;
        er[p] = *(const half8*)((const _Float16*)(ybase + (size_t)(b * DIMC + d) * 131072) + blockIdx.x * 64 + jj);
    }
#pragma unroll
    for (int p = 0; p < 4; ++p) {
        const int idx = p * 256 + t, d = idx >> 3, jj = (idx & 7) * 8;
#pragma unroll
        for (int e = 0; e < 8; ++e) EB[jj + e][d ^ ((((jj + e) >> 2) & 7) << 3)] = er[p][e];
    }
    __syncthreads();

    for (int it = 0; it < TILES; ++it) {
        const int j0 = (blockIdx.x + GRIDX * it) * 64;
        if (it < TILES - 1) {
            const int j0n = (blockIdx.x + GRIDX * (it + 1)) * 64;
#pragma unroll
            for (int p = 0; p < 4; ++p) {
                const int idx = p * 256 + t, d = idx >> 3, jj = (idx & 7) * 8;
                er[p] = *(const half8*)((const _Float16*)(ybase + (size_t)(b * DIMC + d) * 131072) + j0n + jj);
            }
        }
        {
            half8 bf[4][4];
#pragma unroll
            for (int nt = 0; nt < 4; ++nt) {
                const int sb = ((4 * nt + (l15 >> 2)) & 7) << 3;
#pragma unroll
                for (int kc = 0; kc < 4; ++kc)
                    bf[nt][kc] = *(const half8*)(&EB[nt * 16 + l15][(kc * 32 + 8 * g) ^ sb]);
            }
#pragma unroll
            for (int mi = 0; mi < 2; ++mi) {
                const int o0 = (w * 2 + mi) * 16 + g * 4;
                f32x4 acc[4];
#pragma unroll
                for (int nt = 0; nt < 4; ++nt) acc[nt] = (f32x4){0.f, 0.f, 0.f, 0.f};
#pragma unroll
                for (int kc = 0; kc < 4; ++kc)
#pragma unroll
                    for (int nt = 0; nt < 4; ++nt)
                        acc[nt] = __builtin_amdgcn_mfma_f32_16x16x32_f16(ga[mi][kc], bf[nt][kc], acc[nt], 0, 0, 0);
#pragma unroll
                for (int r = 0; r < 4; ++r) {
                    _Float16* yrow = (_Float16*)(ybase + (size_t)(b * DIMC + o0 + r) * 131072 + 65536);
#pragma unroll
                    for (int nt = 0; nt < 4; ++nt) {
                        const float yv = acc[nt][r] + bo[mi][r];
                        ssum += yv;
                        ssq += yv * yv;
                        yrow[j0 + nt * 16 + l15] = (_Float16)yv;
                    }
                }
            }
        }
        __syncthreads();   // EB reads done
        if (it < TILES - 1) {
#pragma unroll
            for (int p = 0; p < 4; ++p) {
                const int idx = p * 256 + t, d = idx >> 3, jj = (idx & 7) * 8;
#pragma unroll
                for (int e = 0; e < 8; ++e) EB[jj + e][d ^ ((((jj + e) >> 2) & 7) << 3)] = er[p][e];
            }
        }
        __syncthreads();   // EB(next) ready
    }
#pragma unroll
    for (int m = 32; m; m >>= 1) { ssum += __shfl_xor(ssum, m); ssq += __shfl_xor(ssq, m); }
    if (lane == 0) { red[w] = ssum; red[4 + w] = ssq; }
    __syncthreads();
    if (t == 0) {
        atomicAdd(&St[b * 2 + 0], red[0] + red[1] + red[2] + red[3]);
        atomicAdd(&St[b * 2 + 1], red[4] + red[5] + red[6] + red[7]);
    }
}

// ---------------- K4: layernorm; read f16 stash (2nd half of own row), write f32 ----------------
__global__ __launch_bounds__(256) void k4_norm(float* __restrict__ out, const float* __restrict__ St,
                                               const float* __restrict__ gamma,
                                               const float* __restrict__ beta) {
    const int o = blockIdx.x;
    const int b = blockIdx.y;
    const int t = threadIdx.x;
    const size_t row = (size_t)b * DIMC + o;
    const float n = (float)DIMC * (float)NTOT;
    const float mean = St[b * 2] / n;
    const float var = St[b * 2 + 1] / n - mean * mean;
    const float rs = rsqrtf(var + 1e-5f);
    const float ga = gamma[o] * rs;
    const float be = beta[o];
    const half8* yh = (const half8*)((const char*)out + row * 131072 + 65536);
    half8 hbuf[16];
#pragma unroll
    for (int i = 0; i < 16; ++i) hbuf[i] = yh[i * 256 + t];
    __syncthreads();  // all reads before any f32 overwrite (stash lives in this row)
    float4* orow = (float4*)(out + row * NTOT);
#pragma unroll
    for (int i = 0; i < 16; ++i) {
        const int e4 = (i * 256 + t) * 2;
        float4 v0, v1;
        v0.x = ((float)hbuf[i][0] - mean) * ga + be;
        v0.y = ((float)hbuf[i][1] - mean) * ga + be;
        v0.z = ((float)hbuf[i][2] - mean) * ga + be;
        v0.w = ((float)hbuf[i][3] - mean) * ga + be;
        v1.x = ((float)hbuf[i][4] - mean) * ga + be;
        v1.y = ((float)hbuf[i][5] - mean) * ga + be;
        v1.z = ((float)hbuf[i][6] - mean) * ga + be;
        v1.w = ((float)hbuf[i][7] - mean) * ga + be;
        orow[e4] = v0;
        orow[e4 + 1] = v1;
    }
}

extern "C" void kernel_launch(void* const* d_in, const int* in_sizes, int n_in,
                              void* d_out, int out_size, void* d_ws, size_t ws_size,
                              hipStream_t stream) {
    const float* x     = (const float*)d_in[0];
    const float* wqkv  = (const float*)d_in[1];
    const float* wout  = (const float*)d_in[2];
    const float* b_out = (const float*)d_in[3];
    const float* gamma = (const float*)d_in[4];
    const float* beta  = (const float*)d_in[5];
    if (ws_size < WS_NEED) return;
    char* ws = (char*)d_ws;
    _Float16* Wb = (_Float16*)(ws + WS_WQKV);
    float* S  = (float*)(ws + WS_S);
    float* Z  = (float*)(ws + WS_Z);
    float* St = (float*)(ws + WS_ST);
    _Float16* G = (_Float16*)(ws + WS_GOFF);  // overwrites Wb region (dead after K1)

    k0_prep<<<325, 256, 0, stream>>>(wqkv, ws);
    k1_kv<<<dim3(GRIDX, 8), 256, 0, stream>>>(x, Wb, S, Z, (char*)d_out);
    k2_g<<<dim3(HEADS, 8), 256, 0, stream>>>(S, Z, wout, G);
    k3_main<<<dim3(GRIDX, 8), 256, 0, stream>>>(G, b_out, (char*)d_out, St);
    k4_norm<<<dim3(128, 8), 256, 0, stream>>>((float*)d_out, St, gamma, beta);
}

// Round 14
// 156.858 us; speedup vs baseline: 2.3685x; 1.0143x over previous
//
#include <hip/hip_runtime.h>

#define BATCH 8
#define DIMC 128
#define NTOT 32768
#define HEADS 4
#define DHEAD 32
#define SCALE_Q 0.17677669529663687f
#define GRIDX 64
#define TILES 8   // GRIDX * TILES * 64 == NTOT

typedef _Float16 half8  __attribute__((ext_vector_type(8)));
typedef _Float16 half4v __attribute__((ext_vector_type(4)));
typedef float    f32x4  __attribute__((ext_vector_type(4)));

// workspace byte offsets (all 16B aligned)
#define WS_WQKV 0        // _Float16[384*128] = 98304 B (dead after K1; G overwrites)
#define WS_S    98304    // float[8*4*32*32]  = 131072 B
#define WS_Z    229376   // float[8*4*32]     = 4096 B
#define WS_ST   233472   // float[16]
#define WS_GOFF 0        // G[b] f16 at ws + b*32768 (overwrites Wb region; Wb dead after K1)
#define WS_NEED 299072

// d_out row layout (each row 131072 B):
//  LOWER half: Ê^T — element (b,j,d) at row (b*128 + (j>>8)), byte (j&255)*256 + d*2.
//              (j0 tiles are 64-aligned so a tile's 64 j's stay in one row; 16KB contiguous.)
//  UPPER half: y f16 stash (K3 writes, K4 reads row-locally then overwrites with f32).

// ---------------- K0: convert Wqkv to f16, zero accumulators ----------------
__global__ void k0_prep(const float* __restrict__ wqkv, char* __restrict__ ws) {
    int i = blockIdx.x * 256 + threadIdx.x;
    _Float16* Wb = (_Float16*)(ws + WS_WQKV);
    float* S  = (float*)(ws + WS_S);
    float* Z  = (float*)(ws + WS_Z);
    float* St = (float*)(ws + WS_ST);
    if (i < 49152) Wb[i] = (_Float16)wqkv[i];
    int j = i - 49152;
    if (j >= 0 && j < 32768) S[j] = 0.f;
    int k = j - 32768;
    if (k >= 0 && k < 1024) Z[k] = 0.f;
    int m = k - 1024;
    if (m >= 0 && m < 16) St[m] = 0.f;
}

// ---------------- K1: qkv projection; k,v -> S,Z; q -> Ê^T (f16, d_out lower halves) ----------------
// af hoisted ((256,1): 192+64=256 VGPR still 2 waves/SIMD); Ê through transposed LDS buffer
// EQT[j][d] so both the q-part store (half4v) and the copy-out (half8 + contiguous 16KB global)
// vectorize. kv-GEMM swapped-operand write, Z via ones-MFMA, en-based vb swizzle (R13-proven).
__global__ __launch_bounds__(256, 1) void k1_kv(const float* __restrict__ x,
                                                const _Float16* __restrict__ Wb,
                                                float* __restrict__ S,
                                                float* __restrict__ Z,
                                                char* __restrict__ ybase) {
    __shared__ _Float16 Xb[64][136];   // x^T tile: [j][c swizzled]
    __shared__ _Float16 KB[128][64];   // exp(k): [h*32+d][j swizzled]
    __shared__ _Float16 VB[128][64];   // v:      [h*32+e][j swizzled]
    __shared__ _Float16 EQT[64][136];  // Ê^T:    [j][d]  (pad 8 -> conflict-free, no XOR)
    const int t = threadIdx.x;
    const int lane = t & 63, w = t >> 6, g = lane >> 4, l15 = lane & 15;
    const int b = blockIdx.y;

    half8 wa[2][4];  // q weight frags (rows 0..127)
    half8 af[4][4];  // k,v weight frags (rows 128..383)
#pragma unroll
    for (int mi = 0; mi < 2; ++mi)
#pragma unroll
        for (int kc = 0; kc < 4; ++kc)
            wa[mi][kc] = *(const half8*)(Wb + (size_t)((w * 2 + mi) * 16 + l15) * 128 + kc * 32 + 8 * g);
#pragma unroll
    for (int mt = 0; mt < 4; ++mt)
#pragma unroll
        for (int kc = 0; kc < 4; ++kc)
            af[mt][kc] = *(const half8*)(Wb + (size_t)(128 + (w * 4 + mt) * 16 + l15) * 128 + kc * 32 + 8 * g);

    half8 vone;
#pragma unroll
    for (int i = 0; i < 8; ++i) vone[i] = (_Float16)1.0f;

    f32x4 sacc[2][2];
#pragma unroll
    for (int dm = 0; dm < 2; ++dm)
#pragma unroll
        for (int en = 0; en < 2; ++en) sacc[dm][en] = (f32x4){0.f, 0.f, 0.f, 0.f};
    f32x4 zacc[2];
    zacc[0] = (f32x4){0.f, 0.f, 0.f, 0.f};
    zacc[1] = (f32x4){0.f, 0.f, 0.f, 0.f};

    const int j4 = t & 15, c0 = t >> 4;
    const int sxw = (j4 & 7) << 3;

    // prologue: load + stage tile 0
    float4 xr[8];
#pragma unroll
    for (int cc = 0; cc < 8; ++cc)
        xr[cc] = *(const float4*)(x + ((size_t)b * DIMC + c0 + 16 * cc) * NTOT + blockIdx.x * 64 + 4 * j4);
#pragma unroll
    for (int cc = 0; cc < 8; ++cc) {
        const int c = c0 + 16 * cc;
        Xb[4 * j4 + 0][c ^ sxw] = (_Float16)xr[cc].x;
        Xb[4 * j4 + 1][c ^ sxw] = (_Float16)xr[cc].y;
        Xb[4 * j4 + 2][c ^ sxw] = (_Float16)xr[cc].z;
        Xb[4 * j4 + 3][c ^ sxw] = (_Float16)xr[cc].w;
    }

    for (int it = 0; it < TILES; ++it) {
        const int j0 = (blockIdx.x + GRIDX * it) * 64;
        __syncthreads();   // (A) Xb ready; prev KB/VB/EQT reads done
        half8 bf[4][4];
#pragma unroll
        for (int nt = 0; nt < 4; ++nt) {
            const int sb = ((4 * nt + (l15 >> 2)) & 7) << 3;
#pragma unroll
            for (int kc = 0; kc < 4; ++kc)
                bf[nt][kc] = *(const half8*)(&Xb[nt * 16 + l15][(kc * 32 + 8 * g) ^ sb]);
        }
        // q part: E=exp(q); colsum over d per column j; Ê = E*SCALE/colsum -> EQT[j][d] (half4v)
        {
            f32x4 eacc[2][4];
#pragma unroll
            for (int mi = 0; mi < 2; ++mi)
#pragma unroll
                for (int nt = 0; nt < 4; ++nt) eacc[mi][nt] = (f32x4){0.f, 0.f, 0.f, 0.f};
#pragma unroll
            for (int mi = 0; mi < 2; ++mi)
#pragma unroll
                for (int kc = 0; kc < 4; ++kc)
#pragma unroll
                    for (int nt = 0; nt < 4; ++nt)
                        eacc[mi][nt] = __builtin_amdgcn_mfma_f32_16x16x32_f16(wa[mi][kc], bf[nt][kc], eacc[mi][nt], 0, 0, 0);
            float ps[4] = {0.f, 0.f, 0.f, 0.f};
#pragma unroll
            for (int mi = 0; mi < 2; ++mi)
#pragma unroll
                for (int nt = 0; nt < 4; ++nt)
#pragma unroll
                    for (int r = 0; r < 4; ++r) {
                        const float e = __expf(eacc[mi][nt][r]);
                        ps[nt] += e;
                        eacc[mi][nt][r] = e;
                    }
            float scn[4];
#pragma unroll
            for (int nt = 0; nt < 4; ++nt) {
                ps[nt] += __shfl_xor(ps[nt], 16);
                ps[nt] += __shfl_xor(ps[nt], 32);
                scn[nt] = SCALE_Q / ps[nt];
            }
#pragma unroll
            for (int mi = 0; mi < 2; ++mi)
#pragma unroll
                for (int nt = 0; nt < 4; ++nt) {
                    half4v p;
#pragma unroll
                    for (int r = 0; r < 4; ++r) p[r] = (_Float16)(eacc[mi][nt][r] * scn[nt]);
                    *(half4v*)(&EQT[nt * 16 + l15][(w * 2 + mi) * 16 + g * 4]) = p;
                }
        }
        // next-tile global loads issued AFTER the q-part (keeps xr out of the peak live set)
        if (it < TILES - 1) {
            const int j0n = (blockIdx.x + GRIDX * (it + 1)) * 64;
#pragma unroll
            for (int cc = 0; cc < 8; ++cc)
                xr[cc] = *(const float4*)(x + ((size_t)b * DIMC + c0 + 16 * cc) * NTOT + j0n + 4 * j4);
        }
        // k,v part — SWAPPED operands: lane = 4 consecutive j at one row -> half4v LDS writes
#pragma unroll
        for (int mt = 0; mt < 4; ++mt) {
            f32x4 a0 = (f32x4){0.f,0.f,0.f,0.f}, a1 = a0, a2 = a0, a3 = a0;
#pragma unroll
            for (int kc = 0; kc < 4; ++kc) {
                a0 = __builtin_amdgcn_mfma_f32_16x16x32_f16(bf[0][kc], af[mt][kc], a0, 0, 0, 0);
                a1 = __builtin_amdgcn_mfma_f32_16x16x32_f16(bf[1][kc], af[mt][kc], a1, 0, 0, 0);
                a2 = __builtin_amdgcn_mfma_f32_16x16x32_f16(bf[2][kc], af[mt][kc], a2, 0, 0, 0);
                a3 = __builtin_amdgcn_mfma_f32_16x16x32_f16(bf[3][kc], af[mt][kc], a3, 0, 0, 0);
            }
            const int row16 = (w * 4 + mt) * 16;
            const int sk = ((mt * 4 + (l15 >> 2)) & 7) << 3;
            if (row16 < 128) {
#pragma unroll
                for (int jt = 0; jt < 4; ++jt) {
                    const f32x4 a = (jt == 0) ? a0 : (jt == 1) ? a1 : (jt == 2) ? a2 : a3;
                    half4v p;
#pragma unroll
                    for (int r = 0; r < 4; ++r) p[r] = (_Float16)__expf(a[r]);
                    *(half4v*)(&KB[row16 + l15][(jt * 16 + g * 4) ^ sk]) = p;
                }
            } else {
#pragma unroll
                for (int jt = 0; jt < 4; ++jt) {
                    const f32x4 a = (jt == 0) ? a0 : (jt == 1) ? a1 : (jt == 2) ? a2 : a3;
                    half4v p;
#pragma unroll
                    for (int r = 0; r < 4; ++r) p[r] = (_Float16)a[r];
                    *(half4v*)(&VB[row16 - 128 + l15][(jt * 16 + g * 4) ^ sk]) = p;
                }
            }
        }
        __syncthreads();   // (B) KB/VB/EQT ready; Xb reads done
        // stage tile it+1 into Xb (overlaps S/Z + copy-out)
        if (it < TILES - 1) {
#pragma unroll
            for (int cc = 0; cc < 8; ++cc) {
                const int c = c0 + 16 * cc;
                Xb[4 * j4 + 0][c ^ sxw] = (_Float16)xr[cc].x;
                Xb[4 * j4 + 1][c ^ sxw] = (_Float16)xr[cc].y;
                Xb[4 * j4 + 2][c ^ sxw] = (_Float16)xr[cc].z;
                Xb[4 * j4 + 3][c ^ sxw] = (_Float16)xr[cc].w;
            }
        }
        // S/Z accumulate (Z via ones-MFMA; vb swizzle en-based)
#pragma unroll
        for (int dm = 0; dm < 2; ++dm) {
            const int sr = ((4 * dm + (l15 >> 2)) & 7) << 3;
            half8 ka0 = *(const half8*)(&KB[w * 32 + dm * 16 + l15][(8 * g) ^ sr]);
            half8 ka1 = *(const half8*)(&KB[w * 32 + dm * 16 + l15][(32 + 8 * g) ^ sr]);
            zacc[dm] = __builtin_amdgcn_mfma_f32_16x16x32_f16(ka0, vone, zacc[dm], 0, 0, 0);
            zacc[dm] = __builtin_amdgcn_mfma_f32_16x16x32_f16(ka1, vone, zacc[dm], 0, 0, 0);
#pragma unroll
            for (int en = 0; en < 2; ++en) {
                const int se = ((4 * en + (l15 >> 2)) & 7) << 3;
                half8 vb0 = *(const half8*)(&VB[w * 32 + en * 16 + l15][(8 * g) ^ se]);
                half8 vb1 = *(const half8*)(&VB[w * 32 + en * 16 + l15][(32 + 8 * g) ^ se]);
                sacc[dm][en] = __builtin_amdgcn_mfma_f32_16x16x32_f16(ka0, vb0, sacc[dm][en], 0, 0, 0);
                sacc[dm][en] = __builtin_amdgcn_mfma_f32_16x16x32_f16(ka1, vb1, sacc[dm][en], 0, 0, 0);
            }
        }
        // Ê^T copy-out: 16KB fully contiguous per tile (256B per j-row)
        {
            char* tb = ybase + (size_t)(b * DIMC + (j0 >> 8)) * 131072 + (size_t)(j0 & 255) * 256;
#pragma unroll
            for (int p = 0; p < 4; ++p) {
                const int idx = p * 256 + t, jl = idx >> 4, d0 = (idx & 15) * 8;
                half8 v = *(const half8*)(&EQT[jl][d0]);
                *(half8*)(tb + (size_t)jl * 256 + d0 * 2) = v;
            }
        }
    }
    // flush Z (every column of zacc holds Z[d]; take l15==0 lanes)
    if (l15 == 0) {
#pragma unroll
        for (int dm = 0; dm < 2; ++dm)
#pragma unroll
            for (int r = 0; r < 4; ++r)
                atomicAdd(&Z[(b * HEADS + w) * DHEAD + dm * 16 + g * 4 + r], zacc[dm][r]);
    }
#pragma unroll
    for (int dm = 0; dm < 2; ++dm)
#pragma unroll
        for (int en = 0; en < 2; ++en)
#pragma unroll
            for (int r = 0; r < 4; ++r)
                atomicAdd(&S[((size_t)(b * HEADS + w) * DHEAD + dm * 16 + g * 4 + r) * DHEAD + en * 16 + l15],
                          sacc[dm][en][r]);
}

// ---------------- K2g: G[b][o][h*32+d] = sum_e wout[o][h*32+e]*S[b][h][d][e]/Z[b][h][d] (f16 -> ws) ----------------
__global__ __launch_bounds__(256) void k2_g(const float* __restrict__ S, const float* __restrict__ Z,
                                            const float* __restrict__ wout, _Float16* __restrict__ G) {
    __shared__ float Sd[32][33];
    const int h = blockIdx.x, b = blockIdx.y;
    const int t = threadIdx.x;
    const float* Sb = S + (size_t)(b * HEADS + h) * 1024;
    const float* Zb = Z + (size_t)(b * HEADS + h) * 32;
    for (int i = t; i < 1024; i += 256) {
        int d = i >> 5;
        Sd[d][i & 31] = Sb[i] / Zb[d];
    }
    __syncthreads();
    const int o = t & 127, dh = (t >> 7) * 16;
    float wrow[32];
#pragma unroll
    for (int e = 0; e < 32; ++e) wrow[e] = wout[o * 128 + h * 32 + e];
    _Float16* Gb = G + (size_t)b * 16384;
#pragma unroll
    for (int dd = 0; dd < 16; ++dd) {
        const int d = dh + dd;
        float acc = 0.f;
#pragma unroll
        for (int e = 0; e < 32; ++e) acc = fmaf(wrow[e], Sd[d][e], acc);
        Gb[o * 128 + h * 32 + d] = (_Float16)acc;
    }
}

// ---------------- K3: streaming y = G @ Ê + b_out -> f16 stash + stats ----------------
// Staging from Ê^T: 4 half8 global loads + 4 b128 LDS writes (was 32 scalar b16 writes).
__global__ __launch_bounds__(256, 2) void k3_main(const _Float16* __restrict__ G,
                                                  const float* __restrict__ b_out,
                                                  char* __restrict__ ybase,
                                                  float* __restrict__ St) {
    __shared__ _Float16 EB[64][136];  // Ê tile: [j][d swizzled]
    __shared__ float red[8];
    const int t = threadIdx.x;
    const int lane = t & 63, w = t >> 6, g = lane >> 4, l15 = lane & 15;
    const int b = blockIdx.y;

    half8 ga[2][4];
    float bo[2][4];
    const _Float16* Gb = G + (size_t)b * 16384;
#pragma unroll
    for (int mi = 0; mi < 2; ++mi) {
        const int o = (w * 2 + mi) * 16 + l15;
#pragma unroll
        for (int kc = 0; kc < 4; ++kc)
            ga[mi][kc] = *(const half8*)(Gb + (size_t)o * 128 + kc * 32 + 8 * g);
#pragma unroll
        for (int r = 0; r < 4; ++r) bo[mi][r] = b_out[(w * 2 + mi) * 16 + g * 4 + r];
    }

    float ssum = 0.f, ssq = 0.f;
    half8 er[4];

    // stage tile 0
    {
        const int jb = blockIdx.x * 64;
        const char* tb = ybase + (size_t)(b * DIMC + (jb >> 8)) * 131072 + (size_t)(jb & 255) * 256;
#pragma unroll
        for (int p = 0; p < 4; ++p) {
            const int idx = p * 256 + t, jl = idx >> 4, d0 = (idx & 15) * 8;
            er[p] = *(const half8*)(tb + (size_t)jl * 256 + d0 * 2);
        }
#pragma unroll
        for (int p = 0; p < 4; ++p) {
            const int idx = p * 256 + t, jl = idx >> 4, d0 = (idx & 15) * 8;
            *(half8*)(&EB[jl][d0 ^ (((jl >> 2) & 7) << 3)]) = er[p];
        }
    }
    __syncthreads();

    for (int it = 0; it < TILES; ++it) {
        const int j0 = (blockIdx.x + GRIDX * it) * 64;
        if (it < TILES - 1) {
            const int jn = (blockIdx.x + GRIDX * (it + 1)) * 64;
            const char* tb = ybase + (size_t)(b * DIMC + (jn >> 8)) * 131072 + (size_t)(jn & 255) * 256;
#pragma unroll
            for (int p = 0; p < 4; ++p) {
                const int idx = p * 256 + t, jl = idx >> 4, d0 = (idx & 15) * 8;
                er[p] = *(const half8*)(tb + (size_t)jl * 256 + d0 * 2);
            }
        }
        {
            half8 bf[4][4];
#pragma unroll
            for (int nt = 0; nt < 4; ++nt) {
                const int sb = ((4 * nt + (l15 >> 2)) & 7) << 3;
#pragma unroll
                for (int kc = 0; kc < 4; ++kc)
                    bf[nt][kc] = *(const half8*)(&EB[nt * 16 + l15][(kc * 32 + 8 * g) ^ sb]);
            }
#pragma unroll
            for (int mi = 0; mi < 2; ++mi) {
                const int o0 = (w * 2 + mi) * 16 + g * 4;
                f32x4 acc[4];
#pragma unroll
                for (int nt = 0; nt < 4; ++nt) acc[nt] = (f32x4){0.f, 0.f, 0.f, 0.f};
#pragma unroll
                for (int kc = 0; kc < 4; ++kc)
#pragma unroll
                    for (int nt = 0; nt < 4; ++nt)
                        acc[nt] = __builtin_amdgcn_mfma_f32_16x16x32_f16(ga[mi][kc], bf[nt][kc], acc[nt], 0, 0, 0);
#pragma unroll
                for (int r = 0; r < 4; ++r) {
                    _Float16* yrow = (_Float16*)(ybase + (size_t)(b * DIMC + o0 + r) * 131072 + 65536);
#pragma unroll
                    for (int nt = 0; nt < 4; ++nt) {
                        const float yv = acc[nt][r] + bo[mi][r];
                        ssum += yv;
                        ssq += yv * yv;
                        yrow[j0 + nt * 16 + l15] = (_Float16)yv;
                    }
                }
            }
        }
        __syncthreads();   // EB reads done
        if (it < TILES - 1) {
#pragma unroll
            for (int p = 0; p < 4; ++p) {
                const int idx = p * 256 + t, jl = idx >> 4, d0 = (idx & 15) * 8;
                *(half8*)(&EB[jl][d0 ^ (((jl >> 2) & 7) << 3)]) = er[p];
            }
        }
        __syncthreads();   // EB(next) ready
    }
#pragma unroll
    for (int m = 32; m; m >>= 1) { ssum += __shfl_xor(ssum, m); ssq += __shfl_xor(ssq, m); }
    if (lane == 0) { red[w] = ssum; red[4 + w] = ssq; }
    __syncthreads();
    if (t == 0) {
        atomicAdd(&St[b * 2 + 0], red[0] + red[1] + red[2] + red[3]);
        atomicAdd(&St[b * 2 + 1], red[4] + red[5] + red[6] + red[7]);
    }
}

// ---------------- K4: layernorm; read f16 stash (2nd half of own row), write f32 ----------------
__global__ __launch_bounds__(256) void k4_norm(float* __restrict__ out, const float* __restrict__ St,
                                               const float* __restrict__ gamma,
                                               const float* __restrict__ beta) {
    const int o = blockIdx.x;
    const int b = blockIdx.y;
    const int t = threadIdx.x;
    const size_t row = (size_t)b * DIMC + o;
    const float n = (float)DIMC * (float)NTOT;
    const float mean = St[b * 2] / n;
    const float var = St[b * 2 + 1] / n - mean * mean;
    const float rs = rsqrtf(var + 1e-5f);
    const float ga = gamma[o] * rs;
    const float be = beta[o];
    const half8* yh = (const half8*)((const char*)out + row * 131072 + 65536);
    half8 hbuf[16];
#pragma unroll
    for (int i = 0; i < 16; ++i) hbuf[i] = yh[i * 256 + t];
    __syncthreads();  // all reads before any f32 overwrite (stash lives in this row)
    float4* orow = (float4*)(out + row * NTOT);
#pragma unroll
    for (int i = 0; i < 16; ++i) {
        const int e4 = (i * 256 + t) * 2;
        float4 v0, v1;
        v0.x = ((float)hbuf[i][0] - mean) * ga + be;
        v0.y = ((float)hbuf[i][1] - mean) * ga + be;
        v0.z = ((float)hbuf[i][2] - mean) * ga + be;
        v0.w = ((float)hbuf[i][3] - mean) * ga + be;
        v1.x = ((float)hbuf[i][4] - mean) * ga + be;
        v1.y = ((float)hbuf[i][5] - mean) * ga + be;
        v1.z = ((float)hbuf[i][6] - mean) * ga + be;
        v1.w = ((float)hbuf[i][7] - mean) * ga + be;
        orow[e4] = v0;
        orow[e4 + 1] = v1;
    }
}

extern "C" void kernel_launch(void* const* d_in, const int* in_sizes, int n_in,
                              void* d_out, int out_size, void* d_ws, size_t ws_size,
                              hipStream_t stream) {
    const float* x     = (const float*)d_in[0];
    const float* wqkv  = (const float*)d_in[1];
    const float* wout  = (const float*)d_in[2];
    const float* b_out = (const float*)d_in[3];
    const float* gamma = (const float*)d_in[4];
    const float* beta  = (const float*)d_in[5];
    if (ws_size < WS_NEED) return;
    char* ws = (char*)d_ws;
    _Float16* Wb = (_Float16*)(ws + WS_WQKV);
    float* S  = (float*)(ws + WS_S);
    float* Z  = (float*)(ws + WS_Z);
    float* St = (float*)(ws + WS_ST);
    _Float16* G = (_Float16*)(ws + WS_GOFF);  // overwrites Wb region (dead after K1)

    k0_prep<<<325, 256, 0, stream>>>(wqkv, ws);
    k1_kv<<<dim3(GRIDX, 8), 256, 0, stream>>>(x, Wb, S, Z, (char*)d_out);
    k2_g<<<dim3(HEADS, 8), 256, 0, stream>>>(S, Z, wout, G);
    k3_main<<<dim3(GRIDX, 8), 256, 0, stream>>>(G, b_out, (char*)d_out, St);
    k4_norm<<<dim3(128, 8), 256, 0, stream>>>((float*)d_out, St, gamma, beta);
}